// Round 12
// baseline (162.951 us; speedup 1.0000x reference)
//
#include <hip/hip_runtime.h>
#include <math.h>

#define EPS 1e-8f

typedef __attribute__((ext_vector_type(8))) short bf16x8;
typedef __attribute__((ext_vector_type(4))) float f32x4;

// ---- ws layout (FLOAT units). frag tile = 1024 bf16 (hi 512 + lo 512) = 512 floats.
#define OFF_F1    0        // L1  cw1 [8 nt][4 kt]
#define OFF_FV1   16384    // V1  ww1 [4][4]
#define OFF_F2    24576    // L2  cw2 [16][4]
#define OFF_FV2   57344    // V2  ww2 [8][2]
#define OFF_F3    65536    // L3  cw3 [2][8]  (20 rows padded to 32)
#define OFF_FV3   73728    // V3  ww3 [1][4]  (10 rows padded to 16)
#define OFF_BASIS 75776    // [1024][10] fp32

__device__ __forceinline__ unsigned short f2bf(float f){
  unsigned u = __float_as_uint(f);
  return (unsigned short)((u + 0x7fffu + ((u >> 16) & 1u)) >> 16);
}
__device__ __forceinline__ float bf2f(unsigned short h){
  return __uint_as_float(((unsigned)h) << 16);
}
__device__ __forceinline__ int fslot(int s, int kt){
  return s ^ kt ^ (((s >> 4) & 1) << 2);
}

// ---------------------------------------------------------------------------
// prep: B-fragment hi/lo bf16 planes for all six layers + fp32 basis.
// Tile (nt,kt), lane s, elem j holds W[nt*16+(s&15)][kt*32+8*(s>>4)+j], 0-pad
// rows >= N.
// ---------------------------------------------------------------------------
__global__ __launch_bounds__(256) void prep_kernel(
    const float* __restrict__ cw1, const float* __restrict__ cw2, const float* __restrict__ cw3,
    const float* __restrict__ ww1, const float* __restrict__ ww2, const float* __restrict__ ww3,
    float* __restrict__ ws)
{
  int id = blockIdx.x * 256 + threadIdx.x;
  unsigned short* wsU = (unsigned short*)ws;
  if (id < 9472) {
    int t = id >> 6, s = id & 63;
    const float* W; int K, N, tloc, dstF, ktbits;
    if (t < 32)       { W = cw1; K = 128; N = 128; tloc = t;       dstF = OFF_F1;  ktbits = 2; }
    else if (t < 48)  { W = ww1; K = 128; N = 64;  tloc = t - 32;  dstF = OFF_FV1; ktbits = 2; }
    else if (t < 112) { W = cw2; K = 128; N = 256; tloc = t - 48;  dstF = OFF_F2;  ktbits = 2; }
    else if (t < 128) { W = ww2; K = 64;  N = 128; tloc = t - 112; dstF = OFF_FV2; ktbits = 1; }
    else if (t < 144) { W = cw3; K = 256; N = 20;  tloc = t - 128; dstF = OFF_F3;  ktbits = 3; }
    else              { W = ww3; K = 128; N = 10;  tloc = t - 144; dstF = OFF_FV3; ktbits = 2; }
    int kt = tloc & ((1 << ktbits) - 1);
    int nt = tloc >> ktbits;
    int row = nt * 16 + (s & 15);
    int kb  = kt * 32 + 8 * (s >> 4);
    bf16x8 hv, lv;
    #pragma unroll
    for (int j = 0; j < 8; ++j) {
      float v = (row < N) ? W[row * K + kb + j] : 0.f;
      unsigned short h = f2bf(v);
      hv[j] = (short)h;
      lv[j] = (short)f2bf(v - bf2f(h));
    }
    unsigned short* dst = wsU + dstF * 2 + tloc * 1024 + s * 8;
    *(bf16x8*)dst = hv;
    *(bf16x8*)(dst + 512) = lv;
    return;
  }
  id -= 9472;
  if (id < 1024) {
    int f = id;
    float tt = (float)f * (1.0f / 1023.0f);
    float v[10]; float s = 0.f;
    #pragma unroll
    for (int p = 0; p < 10; ++p) {
      float d = tt - (float)p * (1.0f / 9.0f);
      float e = expf(-d * d * 50.0f);
      v[p] = e; s += e;
    }
    float inv = 1.0f / (s + EPS);
    #pragma unroll
    for (int p = 0; p < 10; ++p) ws[OFF_BASIS + f*10 + p] = v[p] * inv;
  }
}

#define MFMA __builtin_amdgcn_mfma_f32_16x16x32_bf16

// ---------------------------------------------------------------------------
// Fully fused, all-MFMA MLP (bf16x3) + softmax/tanh tail + combine.
// 32 rows/tile, 512 threads (8 waves), grid 256 (1 block/CU), 2 tiles/block:
// tile k's output stores overlap tile k+1's MLP compute; next-tile x is
// register-prefetched before the store phase.
// ---------------------------------------------------------------------------
__global__ __launch_bounds__(512, 4) void fused_kernel(
    const float* __restrict__ x,
    const float* __restrict__ cb1, const float* __restrict__ cb2, const float* __restrict__ cb3,
    const float* __restrict__ wb1, const float* __restrict__ wb2, const float* __restrict__ wb3,
    const float* __restrict__ ws, float* __restrict__ out)
{
  __shared__ unsigned short H2A[16384];   // h2 A-frags [2 mt][8 kt]; [0..8192) aliases XA
  __shared__ unsigned short H1A[8192];    // h1 A-frags [2 mt][4 kt]
  __shared__ unsigned short HV1A[4096];   // hv1 A-frags [2 mt][2 kt]
  __shared__ unsigned short HV2A[8192];   // hv2 A-frags [2 mt][4 kt]
  __shared__ float vbuf[320];             // logits -> softmax w [32][10]
  __shared__ float cpbuf[640];            // cp sums -> wm [32][20]

  const int tid = threadIdx.x;
  const int l   = tid & 63;
  const int w   = tid >> 6;     // 0..7
  const int g   = l >> 4;       // 0..3
  const int c16 = l & 15;
  unsigned short* XA = H2A;     // x A-frags [2 mt][4 kt], dead after B2
  const unsigned short* wsU = (const unsigned short*)ws;

  // wave-constant tile/pointer setup (tile-invariant)
  const int mt  = w >> 2;            // row tile 0..1
  const int ntv = w & 3;             // V1 col tile
  const int nt0 = (w & 3) * 2, nt1 = nt0 + 1;  // L1 col tiles
  const unsigned short* BV  = wsU + OFF_FV1*2 + (ntv*4)*1024 + l*8;
  const unsigned short* BL0 = wsU + OFF_F1*2  + (nt0*4)*1024 + l*8;
  const unsigned short* BL1 = wsU + OFF_F1*2  + (nt1*4)*1024 + l*8;
  const int v0t = (w & 3) * 2, v1t = v0t + 1;   // hv2 col tiles 0..7
  const unsigned short* C0 = wsU + OFF_FV2*2 + (v0t*2)*1024 + l*8;
  const unsigned short* C1 = wsU + OFF_FV2*2 + (v1t*2)*1024 + l*8;
  const int m0p = (w & 3) * 4, m1p = m0p + 1;
  const unsigned short* D0p = wsU + OFF_F2*2 + (m0p*4)*1024 + l*8;
  const unsigned short* D1p = wsU + OFF_F2*2 + (m1p*4)*1024 + l*8;

  // x prefetch for tile 0
  const int xr = tid >> 4, xk8 = tid & 15;
  float4 xv0, xv1;
  {
    const float4* xg = (const float4*)(x + ((size_t)blockIdx.x * 64 + xr) * 128 + xk8 * 8);
    xv0 = xg[0]; xv1 = xg[1];
  }

  for (int tile = 0; tile < 2; ++tile) {
    const int b0 = blockIdx.x * 64 + tile * 32;

    // ---- P0: split x hi/lo, write XA frags (from prefetched regs)
    {
      float xv[8] = {xv0.x, xv0.y, xv0.z, xv0.w, xv1.x, xv1.y, xv1.z, xv1.w};
      bf16x8 hv, lv;
      #pragma unroll
      for (int j = 0; j < 8; ++j) {
        unsigned short h = f2bf(xv[j]);
        hv[j] = (short)h;
        lv[j] = (short)f2bf(xv[j] - bf2f(h));
      }
      int kt = xk8 >> 2;
      int t0 = (xr >> 4) * 4 + kt;
      int s = (xr & 15) + 16 * (xk8 & 3);
      unsigned short* dst = XA + t0 * 1024 + fslot(s, kt) * 8;
      *(bf16x8*)dst = hv;
      *(bf16x8*)(dst + 512) = lv;
    }

    // P1P2 kt0 B-frag prefetch (global, legal before barrier)
    bf16x8 nvh = *(const bf16x8*)BV;        bf16x8 nvl = *(const bf16x8*)(BV + 512);
    bf16x8 n0h = *(const bf16x8*)BL0;       bf16x8 n0l = *(const bf16x8*)(BL0 + 512);
    bf16x8 n1h = *(const bf16x8*)BL1;       bf16x8 n1l = *(const bf16x8*)(BL1 + 512);

    __syncthreads();   // B1: XA ready

    // ---- P1P2: V1 (1 tile) + L1 (2 tiles) fused over kt, B rotated
    {
      float bv  = wb1[ntv*16 + c16];
      float bl0 = cb1[nt0*16 + c16], bl1 = cb1[nt1*16 + c16];
      f32x4 aVA = {bv, bv, bv, bv},     aVB = {0.f, 0.f, 0.f, 0.f};
      f32x4 aL0A = {bl0, bl0, bl0, bl0}, aL0B = {0.f, 0.f, 0.f, 0.f};
      f32x4 aL1A = {bl1, bl1, bl1, bl1}, aL1B = {0.f, 0.f, 0.f, 0.f};
      #pragma unroll
      for (int kt = 0; kt < 4; ++kt) {
        bf16x8 vh = nvh, vl = nvl, b0h_ = n0h, b0l_ = n0l, b1h_ = n1h, b1l_ = n1l;
        if (kt < 3) {
          nvh = *(const bf16x8*)(BV  + (kt+1)*1024); nvl = *(const bf16x8*)(BV  + (kt+1)*1024 + 512);
          n0h = *(const bf16x8*)(BL0 + (kt+1)*1024); n0l = *(const bf16x8*)(BL0 + (kt+1)*1024 + 512);
          n1h = *(const bf16x8*)(BL1 + (kt+1)*1024); n1l = *(const bf16x8*)(BL1 + (kt+1)*1024 + 512);
        }
        const unsigned short* ap = XA + (mt*4 + kt) * 1024 + fslot(l, kt) * 8;
        bf16x8 ah = *(const bf16x8*)ap;
        bf16x8 al = *(const bf16x8*)(ap + 512);
        aVA = MFMA(ah, vh, aVA, 0,0,0);   aVB = MFMA(ah, vl, aVB, 0,0,0);   aVB = MFMA(al, vh, aVB, 0,0,0);
        aL0A = MFMA(ah, b0h_, aL0A, 0,0,0); aL0B = MFMA(ah, b0l_, aL0B, 0,0,0); aL0B = MFMA(al, b0h_, aL0B, 0,0,0);
        aL1A = MFMA(ah, b1h_, aL1A, 0,0,0); aL1B = MFMA(ah, b1l_, aL1B, 0,0,0); aL1B = MFMA(al, b1h_, aL1B, 0,0,0);
      }
      // V1 epilogue -> HV1A (hv1 width 64)
      {
        int kt2 = ntv >> 1;
        int sb = 16 * ((2*ntv + (c16 >> 3)) & 3);
        unsigned short* tb = HV1A + (mt*2 + kt2) * 1024;
        #pragma unroll
        for (int i = 0; i < 4; ++i) {
          float v = fmaxf(aVA[i] + aVB[i], 0.f);
          int idx = fslot(4*g + i + sb, kt2) * 8 + (c16 & 7);
          unsigned short h = f2bf(v);
          tb[idx] = h; tb[512 + idx] = f2bf(v - bf2f(h));
        }
      }
      // L1 epilogue -> H1A (h1 width 128)
      #pragma unroll
      for (int t2 = 0; t2 < 2; ++t2) {
        int nt = nt0 + t2;
        int kt2 = nt >> 1;
        int sb = 16 * ((2*nt + (c16 >> 3)) & 3);
        unsigned short* tb = H1A + (mt*4 + kt2) * 1024;
        #pragma unroll
        for (int i = 0; i < 4; ++i) {
          float v = t2 ? fmaxf(aL1A[i] + aL1B[i], 0.f) : fmaxf(aL0A[i] + aL0B[i], 0.f);
          int idx = fslot(4*g + i + sb, kt2) * 8 + (c16 & 7);
          unsigned short h = f2bf(v);
          tb[idx] = h; tb[512 + idx] = f2bf(v - bf2f(h));
        }
      }
    }

    // P3 B-frag preloads (V2: 2 tiles x 2 kt), issued before the barrier
    bf16x8 c0h0 = *(const bf16x8*)C0;          bf16x8 c0l0 = *(const bf16x8*)(C0 + 512);
    bf16x8 c0h1 = *(const bf16x8*)(C0 + 1024); bf16x8 c0l1 = *(const bf16x8*)(C0 + 1536);
    bf16x8 c1h0 = *(const bf16x8*)C1;          bf16x8 c1l0 = *(const bf16x8*)(C1 + 512);
    bf16x8 c1h1 = *(const bf16x8*)(C1 + 1024); bf16x8 c1l1 = *(const bf16x8*)(C1 + 1536);

    // P4 pp=0 kt0 B-frag prefetch
    bf16x8 pd0h = *(const bf16x8*)D0p, pd0l = *(const bf16x8*)(D0p + 512);
    bf16x8 pd1h = *(const bf16x8*)D1p, pd1l = *(const bf16x8*)(D1p + 512);

    __syncthreads();   // B2: H1A/HV1A ready, XA dead

    // ---- P3: V2 (2 tiles/wave, K=64) -> HV2A frags
    {
      float bb0 = wb2[v0t*16 + c16], bb1 = wb2[v1t*16 + c16];
      f32x4 a0A = {bb0, bb0, bb0, bb0}, a0B = {0.f, 0.f, 0.f, 0.f};
      f32x4 a1A = {bb1, bb1, bb1, bb1}, a1B = {0.f, 0.f, 0.f, 0.f};
      {
        const unsigned short* ap = HV1A + (mt*2 + 0) * 1024 + fslot(l, 0) * 8;
        bf16x8 ah = *(const bf16x8*)ap, al = *(const bf16x8*)(ap + 512);
        a0A = MFMA(ah, c0h0, a0A, 0,0,0); a0B = MFMA(ah, c0l0, a0B, 0,0,0); a0B = MFMA(al, c0h0, a0B, 0,0,0);
        a1A = MFMA(ah, c1h0, a1A, 0,0,0); a1B = MFMA(ah, c1l0, a1B, 0,0,0); a1B = MFMA(al, c1h0, a1B, 0,0,0);
      }
      {
        const unsigned short* ap = HV1A + (mt*2 + 1) * 1024 + fslot(l, 1) * 8;
        bf16x8 ah = *(const bf16x8*)ap, al = *(const bf16x8*)(ap + 512);
        a0A = MFMA(ah, c0h1, a0A, 0,0,0); a0B = MFMA(ah, c0l1, a0B, 0,0,0); a0B = MFMA(al, c0h1, a0B, 0,0,0);
        a1A = MFMA(ah, c1h1, a1A, 0,0,0); a1B = MFMA(ah, c1l1, a1B, 0,0,0); a1B = MFMA(al, c1h1, a1B, 0,0,0);
      }
      #pragma unroll
      for (int t2 = 0; t2 < 2; ++t2) {
        int nt = v0t + t2;
        int kt2 = nt >> 1;
        int sb = 16 * ((2*nt + (c16 >> 3)) & 3);
        unsigned short* tb = HV2A + (mt*4 + kt2) * 1024;
        #pragma unroll
        for (int i = 0; i < 4; ++i) {
          float v = t2 ? fmaxf(a1A[i] + a1B[i], 0.f) : fmaxf(a0A[i] + a0B[i], 0.f);
          int idx = fslot(4*g + i + sb, kt2) * 8 + (c16 & 7);
          unsigned short h = f2bf(v);
          tb[idx] = h; tb[512 + idx] = f2bf(v - bf2f(h));
        }
      }
    }

    // ---- P4: L2 (4 tiles/wave in 2 pairs, K=128) -> H2A frags, B rotated
    #pragma unroll
    for (int pp = 0; pp < 2; ++pp) {
      const int m0 = (w & 3) * 4 + pp * 2, m1 = m0 + 1;   // h2 col tiles 0..15
      const unsigned short* D0 = wsU + OFF_F2*2 + (m0*4)*1024 + l*8;
      const unsigned short* D1 = wsU + OFF_F2*2 + (m1*4)*1024 + l*8;
      bf16x8 nd0h = pp ? *(const bf16x8*)D0 : pd0h;
      bf16x8 nd0l = pp ? *(const bf16x8*)(D0 + 512) : pd0l;
      bf16x8 nd1h = pp ? *(const bf16x8*)D1 : pd1h;
      bf16x8 nd1l = pp ? *(const bf16x8*)(D1 + 512) : pd1l;
      float bb0 = cb2[m0*16 + c16], bb1 = cb2[m1*16 + c16];
      f32x4 a0A = {bb0, bb0, bb0, bb0}, a0B = {0.f, 0.f, 0.f, 0.f};
      f32x4 a1A = {bb1, bb1, bb1, bb1}, a1B = {0.f, 0.f, 0.f, 0.f};
      #pragma unroll
      for (int kt = 0; kt < 4; ++kt) {
        bf16x8 d0h = nd0h, d0l = nd0l, d1h = nd1h, d1l = nd1l;
        if (kt < 3) {
          nd0h = *(const bf16x8*)(D0 + (kt+1)*1024); nd0l = *(const bf16x8*)(D0 + (kt+1)*1024 + 512);
          nd1h = *(const bf16x8*)(D1 + (kt+1)*1024); nd1l = *(const bf16x8*)(D1 + (kt+1)*1024 + 512);
        }
        const unsigned short* ap = H1A + (mt*4 + kt) * 1024 + fslot(l, kt) * 8;
        bf16x8 ah = *(const bf16x8*)ap, al = *(const bf16x8*)(ap + 512);
        a0A = MFMA(ah, d0h, a0A, 0,0,0); a0B = MFMA(ah, d0l, a0B, 0,0,0); a0B = MFMA(al, d0h, a0B, 0,0,0);
        a1A = MFMA(ah, d1h, a1A, 0,0,0); a1B = MFMA(ah, d1l, a1B, 0,0,0); a1B = MFMA(al, d1h, a1B, 0,0,0);
      }
      #pragma unroll
      for (int t2 = 0; t2 < 2; ++t2) {
        int nt = m0 + t2;
        int kt2 = nt >> 1;
        int sb = 16 * ((2*nt + (c16 >> 3)) & 3);
        unsigned short* tb = H2A + (mt*8 + kt2) * 1024;
        #pragma unroll
        for (int i = 0; i < 4; ++i) {
          float v = t2 ? fmaxf(a1A[i] + a1B[i], 0.f) : fmaxf(a0A[i] + a0B[i], 0.f);
          int idx = fslot(4*g + i + sb, kt2) * 8 + (c16 & 7);
          unsigned short h = f2bf(v);
          tb[idx] = h; tb[512 + idx] = f2bf(v - bf2f(h));
        }
      }
    }

    // P5 kt0 B-frag prefetch + tail basis load
    bf16x8 p5h = {}, p5l = {};
    if (w < 4) {
      const unsigned short* F3p = wsU + OFF_F3*2 + ((w & 1)*8)*1024 + l*8;
      p5h = *(const bf16x8*)F3p; p5l = *(const bf16x8*)(F3p + 512);
    } else if (w < 6) {
      const unsigned short* FVp = wsU + OFF_FV3*2 + l*8;
      p5h = *(const bf16x8*)FVp; p5l = *(const bf16x8*)(FVp + 512);
    }
    const int f0 = tid * 2;
    float bas[20];
    {
      const float4* bp = (const float4*)((ws + OFF_BASIS) + f0 * 10);
      #pragma unroll
      for (int i = 0; i < 5; ++i) {
        float4 v = bp[i];
        bas[4*i+0] = v.x; bas[4*i+1] = v.y; bas[4*i+2] = v.z; bas[4*i+3] = v.w;
      }
    }
    __syncthreads();   // B3: H2A/HV2A ready

    // ---- P5: V3+L3 via MFMA (unique owners -> plain LDS stores)
    if (w < 4) {        // L3: tile (lmt = w>>1, lnt = w&1), K=256
      const int lmt = w >> 1, lnt = w & 1;
      const unsigned short* F3 = wsU + OFF_F3*2 + (lnt*8)*1024 + l*8;
      f32x4 aA = {0.f, 0.f, 0.f, 0.f}, aB = {0.f, 0.f, 0.f, 0.f};
      bf16x8 nbh = p5h, nbl = p5l;
      #pragma unroll
      for (int kt = 0; kt < 8; ++kt) {
        bf16x8 bh = nbh, bl = nbl;
        if (kt < 7) {
          nbh = *(const bf16x8*)(F3 + (kt+1)*1024); nbl = *(const bf16x8*)(F3 + (kt+1)*1024 + 512);
        }
        const unsigned short* ap = H2A + (lmt*8 + kt) * 1024 + fslot(l, kt) * 8;
        bf16x8 ah = *(const bf16x8*)ap, al = *(const bf16x8*)(ap + 512);
        aA = MFMA(ah, bh, aA, 0,0,0); aB = MFMA(ah, bl, aB, 0,0,0); aB = MFMA(al, bh, aB, 0,0,0);
      }
      #pragma unroll
      for (int i = 0; i < 4; ++i) {
        int r = lmt*16 + 4*g + i, c = lnt*16 + c16;
        if (c < 20) cpbuf[r*20 + c] = aA[i] + aB[i];
      }
    } else if (w < 6) { // V3: tile (vmt = w-4), K=128
      const int vmt = w - 4;
      const unsigned short* FV = wsU + OFF_FV3*2 + l*8;
      f32x4 aA = {0.f, 0.f, 0.f, 0.f}, aB = {0.f, 0.f, 0.f, 0.f};
      #pragma unroll
      for (int kt = 0; kt < 4; ++kt) {
        bf16x8 bh = kt ? *(const bf16x8*)(FV + kt*1024) : p5h;
        bf16x8 bl = kt ? *(const bf16x8*)(FV + kt*1024 + 512) : p5l;
        const unsigned short* ap = HV2A + (vmt*4 + kt) * 1024 + fslot(l, kt) * 8;
        bf16x8 ah = *(const bf16x8*)ap, al = *(const bf16x8*)(ap + 512);
        aA = MFMA(ah, bh, aA, 0,0,0); aB = MFMA(ah, bl, aB, 0,0,0); aB = MFMA(al, bh, aB, 0,0,0);
      }
      #pragma unroll
      for (int i = 0; i < 4; ++i) {
        int r = vmt*16 + 4*g + i;
        if (c16 < 10) vbuf[r*10 + c16] = aA[i] + aB[i];
      }
    }
    __syncthreads();   // B4: vbuf(logits) + cpbuf(cp sums) ready

    // ---- P6: softmax + wm (tid<32, one row each)
    if (tid < 32) {
      float lg[10]; float m = -1e30f;
      #pragma unroll
      for (int j = 0; j < 10; ++j) { lg[j] = vbuf[tid*10 + j] + wb3[j]; m = fmaxf(m, lg[j]); }
      float s = 0.f;
      #pragma unroll
      for (int j = 0; j < 10; ++j) { float e = expf(lg[j] - m); lg[j] = e; s += e; }
      float inv = __builtin_amdgcn_rcpf(s);
      #pragma unroll
      for (int j = 0; j < 10; ++j) vbuf[tid*10 + j] = lg[j] * inv;
      #pragma unroll
      for (int p = 0; p < 10; ++p) {
        float s0 = cpbuf[tid*20 + 2*p]     + cb3[2*p];
        float s1 = cpbuf[tid*20 + 2*p + 1] + cb3[2*p + 1];
        float cm = 0.5f * (tanhf(s0) + tanhf(s1));
        cpbuf[tid*20 + p] = vbuf[tid*10 + p] * cm;
      }
    }
    __syncthreads();   // B5: w in vbuf[.][0..10), wm in cpbuf[.*20 + 0..10)

    // ---- next-tile x prefetch (before the store phase; hides HBM latency)
    if (tile == 0) {
      const float4* xg = (const float4*)(x + ((size_t)blockIdx.x * 64 + 32 + xr) * 128 + xk8 * 8);
      xv0 = xg[0]; xv1 = xg[1];
    }

    // ---- P7: combine + output. thread = 2 consecutive f-cols x 32 rows.
    for (int rr = 0; rr < 32; ++rr) {
      float wv[10], wm[10];
      #pragma unroll
      for (int p = 0; p < 10; p += 2) {
        float2 a = *(const float2*)(vbuf + rr*10 + p);
        wv[p] = a.x; wv[p+1] = a.y;
        float2 b = *(const float2*)(cpbuf + rr*20 + p);
        wm[p] = b.x; wm[p+1] = b.y;
      }
      float n0 = 0.f, d0 = EPS, n1 = 0.f, d1 = EPS;
      #pragma unroll
      for (int p = 0; p < 10; ++p) {
        n0 = fmaf(bas[p],      wm[p], n0);
        d0 = fmaf(bas[p],      wv[p], d0);
        n1 = fmaf(bas[10 + p], wm[p], n1);
        d1 = fmaf(bas[10 + p], wv[p], d1);
      }
      float2 o;
      o.x = n0 * __builtin_amdgcn_rcpf(d0);
      o.y = n1 * __builtin_amdgcn_rcpf(d1);
      *(float2*)(out + (size_t)(b0 + rr) * 1024 + f0) = o;
    }
  }
}

// ---------------------------------------------------------------------------
extern "C" void kernel_launch(void* const* d_in, const int* in_sizes, int n_in,
                              void* d_out, int out_size, void* d_ws, size_t ws_size,
                              hipStream_t stream)
{
  const float* x   = (const float*)d_in[0];
  const float* cw1 = (const float*)d_in[1];
  const float* cb1 = (const float*)d_in[2];
  const float* cw2 = (const float*)d_in[3];
  const float* cb2 = (const float*)d_in[4];
  const float* cw3 = (const float*)d_in[5];
  const float* cb3 = (const float*)d_in[6];
  const float* ww1 = (const float*)d_in[7];
  const float* wb1 = (const float*)d_in[8];
  const float* ww2 = (const float*)d_in[9];
  const float* wb2 = (const float*)d_in[10];
  const float* ww3 = (const float*)d_in[11];
  const float* wb3 = (const float*)d_in[12];
  float* ws  = (float*)d_ws;
  float* out = (float*)d_out;

  prep_kernel<<<41, 256, 0, stream>>>(cw1, cw2, cw3, ww1, ww2, ww3, ws);
  fused_kernel<<<256, 512, 0, stream>>>(x, cb1, cb2, cb3, wb1, wb2, wb3, ws, out);
}

// Round 13
// 48.705 us; speedup vs baseline: 3.3457x; 3.3457x over previous
//
#include <hip/hip_runtime.h>
#include <math.h>

#define EPS 1e-8f

typedef __attribute__((ext_vector_type(8))) short bf16x8;
typedef __attribute__((ext_vector_type(4))) float f32x4;

// ---- ws layout (FLOAT units). frag tile = 1024 bf16 (hi 512 + lo 512) = 512 floats.
#define OFF_F1    0        // L1  cw1 [8 nt][4 kt]
#define OFF_FV1   16384    // V1  ww1 [4][4]
#define OFF_F2    24576    // L2  cw2 [16][4]
#define OFF_FV2   57344    // V2  ww2 [8][2]
#define OFF_F3    65536    // L3  cw3 [2][8]  (20 rows padded to 32)
#define OFF_FV3   73728    // V3  ww3 [1][4]  (10 rows padded to 16)
#define OFF_BASIS 75776    // [1024][10] fp32

__device__ __forceinline__ unsigned short f2bf(float f){
  unsigned u = __float_as_uint(f);
  return (unsigned short)((u + 0x7fffu + ((u >> 16) & 1u)) >> 16);
}
__device__ __forceinline__ float bf2f(unsigned short h){
  return __uint_as_float(((unsigned)h) << 16);
}
__device__ __forceinline__ int fslot(int s, int kt){
  return s ^ kt ^ (((s >> 4) & 1) << 2);
}

// ---------------------------------------------------------------------------
// prep: B-fragment hi/lo bf16 planes for all six layers + fp32 basis.
// ---------------------------------------------------------------------------
__global__ __launch_bounds__(256) void prep_kernel(
    const float* __restrict__ cw1, const float* __restrict__ cw2, const float* __restrict__ cw3,
    const float* __restrict__ ww1, const float* __restrict__ ww2, const float* __restrict__ ww3,
    float* __restrict__ ws)
{
  int id = blockIdx.x * 256 + threadIdx.x;
  unsigned short* wsU = (unsigned short*)ws;
  if (id < 9472) {
    int t = id >> 6, s = id & 63;
    const float* W; int K, N, tloc, dstF, ktbits;
    if (t < 32)       { W = cw1; K = 128; N = 128; tloc = t;       dstF = OFF_F1;  ktbits = 2; }
    else if (t < 48)  { W = ww1; K = 128; N = 64;  tloc = t - 32;  dstF = OFF_FV1; ktbits = 2; }
    else if (t < 112) { W = cw2; K = 128; N = 256; tloc = t - 48;  dstF = OFF_F2;  ktbits = 2; }
    else if (t < 128) { W = ww2; K = 64;  N = 128; tloc = t - 112; dstF = OFF_FV2; ktbits = 1; }
    else if (t < 144) { W = cw3; K = 256; N = 20;  tloc = t - 128; dstF = OFF_F3;  ktbits = 3; }
    else              { W = ww3; K = 128; N = 10;  tloc = t - 144; dstF = OFF_FV3; ktbits = 2; }
    int kt = tloc & ((1 << ktbits) - 1);
    int nt = tloc >> ktbits;
    int row = nt * 16 + (s & 15);
    int kb  = kt * 32 + 8 * (s >> 4);
    bf16x8 hv, lv;
    #pragma unroll
    for (int j = 0; j < 8; ++j) {
      float v = (row < N) ? W[row * K + kb + j] : 0.f;
      unsigned short h = f2bf(v);
      hv[j] = (short)h;
      lv[j] = (short)f2bf(v - bf2f(h));
    }
    unsigned short* dst = wsU + dstF * 2 + tloc * 1024 + s * 8;
    *(bf16x8*)dst = hv;
    *(bf16x8*)(dst + 512) = lv;
    return;
  }
  id -= 9472;
  if (id < 1024) {
    int f = id;
    float tt = (float)f * (1.0f / 1023.0f);
    float v[10]; float s = 0.f;
    #pragma unroll
    for (int p = 0; p < 10; ++p) {
      float d = tt - (float)p * (1.0f / 9.0f);
      float e = expf(-d * d * 50.0f);
      v[p] = e; s += e;
    }
    float inv = 1.0f / (s + EPS);
    #pragma unroll
    for (int p = 0; p < 10; ++p) ws[OFF_BASIS + f*10 + p] = v[p] * inv;
  }
}

#define MFMA __builtin_amdgcn_mfma_f32_16x16x32_bf16

// ---------------------------------------------------------------------------
// Fully fused, all-MFMA MLP (bf16x3) + softmax/tanh tail + combine.
// 32 rows/tile, 512 threads (8 waves), grid 256 (1 block/CU), 2 tiles/block
// FULLY UNROLLED (r12's runtime loop caused scratch spills; compile-time
// tile index restores r11-style straight-line regalloc). launch_bounds(512,2)
// raises the VGPR cap to 256 since only 1 block/CU is resident.
// ---------------------------------------------------------------------------
__global__ __launch_bounds__(512, 2) void fused_kernel(
    const float* __restrict__ x,
    const float* __restrict__ cb1, const float* __restrict__ cb2, const float* __restrict__ cb3,
    const float* __restrict__ wb1, const float* __restrict__ wb2, const float* __restrict__ wb3,
    const float* __restrict__ ws, float* __restrict__ out)
{
  __shared__ unsigned short H2A[16384];   // h2 A-frags [2 mt][8 kt]; [0..8192) aliases XA
  __shared__ unsigned short H1A[8192];    // h1 A-frags [2 mt][4 kt]
  __shared__ unsigned short HV1A[4096];   // hv1 A-frags [2 mt][2 kt]
  __shared__ unsigned short HV2A[8192];   // hv2 A-frags [2 mt][4 kt]
  __shared__ float vbuf[320];             // logits -> softmax w [32][10]
  __shared__ float cpbuf[640];            // cp sums -> wm [32][20]

  const int tid = threadIdx.x;
  const int l   = tid & 63;
  const int w   = tid >> 6;     // 0..7
  const int g   = l >> 4;       // 0..3
  const int c16 = l & 15;
  unsigned short* XA = H2A;     // x A-frags [2 mt][4 kt], dead after B2
  const unsigned short* wsU = (const unsigned short*)ws;

  // wave-constant tile/pointer setup (tile-invariant)
  const int mt  = w >> 2;            // row tile 0..1
  const int ntv = w & 3;             // V1 col tile
  const int nt0 = (w & 3) * 2, nt1 = nt0 + 1;  // L1 col tiles
  const unsigned short* BV  = wsU + OFF_FV1*2 + (ntv*4)*1024 + l*8;
  const unsigned short* BL0 = wsU + OFF_F1*2  + (nt0*4)*1024 + l*8;
  const unsigned short* BL1 = wsU + OFF_F1*2  + (nt1*4)*1024 + l*8;
  const int v0t = (w & 3) * 2, v1t = v0t + 1;   // hv2 col tiles 0..7
  const unsigned short* C0 = wsU + OFF_FV2*2 + (v0t*2)*1024 + l*8;
  const unsigned short* C1 = wsU + OFF_FV2*2 + (v1t*2)*1024 + l*8;
  const int m0p = (w & 3) * 4, m1p = m0p + 1;
  const unsigned short* D0p = wsU + OFF_F2*2 + (m0p*4)*1024 + l*8;
  const unsigned short* D1p = wsU + OFF_F2*2 + (m1p*4)*1024 + l*8;

  // x prefetch for tile 0
  const int xr = tid >> 4, xk8 = tid & 15;
  float4 xv0, xv1;
  {
    const float4* xg = (const float4*)(x + ((size_t)blockIdx.x * 64 + xr) * 128 + xk8 * 8);
    xv0 = xg[0]; xv1 = xg[1];
  }

  #pragma unroll
  for (int tile = 0; tile < 2; ++tile) {
    const int b0 = blockIdx.x * 64 + tile * 32;

    // ---- P0: split x hi/lo, write XA frags (from prefetched regs)
    {
      float xv[8] = {xv0.x, xv0.y, xv0.z, xv0.w, xv1.x, xv1.y, xv1.z, xv1.w};
      bf16x8 hv, lv;
      #pragma unroll
      for (int j = 0; j < 8; ++j) {
        unsigned short h = f2bf(xv[j]);
        hv[j] = (short)h;
        lv[j] = (short)f2bf(xv[j] - bf2f(h));
      }
      int kt = xk8 >> 2;
      int t0 = (xr >> 4) * 4 + kt;
      int s = (xr & 15) + 16 * (xk8 & 3);
      unsigned short* dst = XA + t0 * 1024 + fslot(s, kt) * 8;
      *(bf16x8*)dst = hv;
      *(bf16x8*)(dst + 512) = lv;
    }

    // P1P2 kt0 B-frag prefetch (global, legal before barrier)
    bf16x8 nvh = *(const bf16x8*)BV;        bf16x8 nvl = *(const bf16x8*)(BV + 512);
    bf16x8 n0h = *(const bf16x8*)BL0;       bf16x8 n0l = *(const bf16x8*)(BL0 + 512);
    bf16x8 n1h = *(const bf16x8*)BL1;       bf16x8 n1l = *(const bf16x8*)(BL1 + 512);

    __syncthreads();   // B1: XA ready

    // ---- P1P2: V1 (1 tile) + L1 (2 tiles) fused over kt, B rotated
    {
      float bv  = wb1[ntv*16 + c16];
      float bl0 = cb1[nt0*16 + c16], bl1 = cb1[nt1*16 + c16];
      f32x4 aVA = {bv, bv, bv, bv},     aVB = {0.f, 0.f, 0.f, 0.f};
      f32x4 aL0A = {bl0, bl0, bl0, bl0}, aL0B = {0.f, 0.f, 0.f, 0.f};
      f32x4 aL1A = {bl1, bl1, bl1, bl1}, aL1B = {0.f, 0.f, 0.f, 0.f};
      #pragma unroll
      for (int kt = 0; kt < 4; ++kt) {
        bf16x8 vh = nvh, vl = nvl, b0h_ = n0h, b0l_ = n0l, b1h_ = n1h, b1l_ = n1l;
        if (kt < 3) {
          nvh = *(const bf16x8*)(BV  + (kt+1)*1024); nvl = *(const bf16x8*)(BV  + (kt+1)*1024 + 512);
          n0h = *(const bf16x8*)(BL0 + (kt+1)*1024); n0l = *(const bf16x8*)(BL0 + (kt+1)*1024 + 512);
          n1h = *(const bf16x8*)(BL1 + (kt+1)*1024); n1l = *(const bf16x8*)(BL1 + (kt+1)*1024 + 512);
        }
        const unsigned short* ap = XA + (mt*4 + kt) * 1024 + fslot(l, kt) * 8;
        bf16x8 ah = *(const bf16x8*)ap;
        bf16x8 al = *(const bf16x8*)(ap + 512);
        aVA = MFMA(ah, vh, aVA, 0,0,0);   aVB = MFMA(ah, vl, aVB, 0,0,0);   aVB = MFMA(al, vh, aVB, 0,0,0);
        aL0A = MFMA(ah, b0h_, aL0A, 0,0,0); aL0B = MFMA(ah, b0l_, aL0B, 0,0,0); aL0B = MFMA(al, b0h_, aL0B, 0,0,0);
        aL1A = MFMA(ah, b1h_, aL1A, 0,0,0); aL1B = MFMA(ah, b1l_, aL1B, 0,0,0); aL1B = MFMA(al, b1h_, aL1B, 0,0,0);
      }
      // V1 epilogue -> HV1A (hv1 width 64)
      {
        int kt2 = ntv >> 1;
        int sb = 16 * ((2*ntv + (c16 >> 3)) & 3);
        unsigned short* tb = HV1A + (mt*2 + kt2) * 1024;
        #pragma unroll
        for (int i = 0; i < 4; ++i) {
          float v = fmaxf(aVA[i] + aVB[i], 0.f);
          int idx = fslot(4*g + i + sb, kt2) * 8 + (c16 & 7);
          unsigned short h = f2bf(v);
          tb[idx] = h; tb[512 + idx] = f2bf(v - bf2f(h));
        }
      }
      // L1 epilogue -> H1A (h1 width 128)
      #pragma unroll
      for (int t2 = 0; t2 < 2; ++t2) {
        int nt = nt0 + t2;
        int kt2 = nt >> 1;
        int sb = 16 * ((2*nt + (c16 >> 3)) & 3);
        unsigned short* tb = H1A + (mt*4 + kt2) * 1024;
        #pragma unroll
        for (int i = 0; i < 4; ++i) {
          float v = t2 ? fmaxf(aL1A[i] + aL1B[i], 0.f) : fmaxf(aL0A[i] + aL0B[i], 0.f);
          int idx = fslot(4*g + i + sb, kt2) * 8 + (c16 & 7);
          unsigned short h = f2bf(v);
          tb[idx] = h; tb[512 + idx] = f2bf(v - bf2f(h));
        }
      }
    }

    // P3 B-frag preloads (V2: 2 tiles x 2 kt), issued before the barrier
    bf16x8 c0h0 = *(const bf16x8*)C0;          bf16x8 c0l0 = *(const bf16x8*)(C0 + 512);
    bf16x8 c0h1 = *(const bf16x8*)(C0 + 1024); bf16x8 c0l1 = *(const bf16x8*)(C0 + 1536);
    bf16x8 c1h0 = *(const bf16x8*)C1;          bf16x8 c1l0 = *(const bf16x8*)(C1 + 512);
    bf16x8 c1h1 = *(const bf16x8*)(C1 + 1024); bf16x8 c1l1 = *(const bf16x8*)(C1 + 1536);

    // P4 pp=0 kt0 B-frag prefetch
    bf16x8 pd0h = *(const bf16x8*)D0p, pd0l = *(const bf16x8*)(D0p + 512);
    bf16x8 pd1h = *(const bf16x8*)D1p, pd1l = *(const bf16x8*)(D1p + 512);

    __syncthreads();   // B2: H1A/HV1A ready, XA dead

    // ---- P3: V2 (2 tiles/wave, K=64) -> HV2A frags
    {
      float bb0 = wb2[v0t*16 + c16], bb1 = wb2[v1t*16 + c16];
      f32x4 a0A = {bb0, bb0, bb0, bb0}, a0B = {0.f, 0.f, 0.f, 0.f};
      f32x4 a1A = {bb1, bb1, bb1, bb1}, a1B = {0.f, 0.f, 0.f, 0.f};
      {
        const unsigned short* ap = HV1A + (mt*2 + 0) * 1024 + fslot(l, 0) * 8;
        bf16x8 ah = *(const bf16x8*)ap, al = *(const bf16x8*)(ap + 512);
        a0A = MFMA(ah, c0h0, a0A, 0,0,0); a0B = MFMA(ah, c0l0, a0B, 0,0,0); a0B = MFMA(al, c0h0, a0B, 0,0,0);
        a1A = MFMA(ah, c1h0, a1A, 0,0,0); a1B = MFMA(ah, c1l0, a1B, 0,0,0); a1B = MFMA(al, c1h0, a1B, 0,0,0);
      }
      {
        const unsigned short* ap = HV1A + (mt*2 + 1) * 1024 + fslot(l, 1) * 8;
        bf16x8 ah = *(const bf16x8*)ap, al = *(const bf16x8*)(ap + 512);
        a0A = MFMA(ah, c0h1, a0A, 0,0,0); a0B = MFMA(ah, c0l1, a0B, 0,0,0); a0B = MFMA(al, c0h1, a0B, 0,0,0);
        a1A = MFMA(ah, c1h1, a1A, 0,0,0); a1B = MFMA(ah, c1l1, a1B, 0,0,0); a1B = MFMA(al, c1h1, a1B, 0,0,0);
      }
      #pragma unroll
      for (int t2 = 0; t2 < 2; ++t2) {
        int nt = v0t + t2;
        int kt2 = nt >> 1;
        int sb = 16 * ((2*nt + (c16 >> 3)) & 3);
        unsigned short* tb = HV2A + (mt*4 + kt2) * 1024;
        #pragma unroll
        for (int i = 0; i < 4; ++i) {
          float v = t2 ? fmaxf(a1A[i] + a1B[i], 0.f) : fmaxf(a0A[i] + a0B[i], 0.f);
          int idx = fslot(4*g + i + sb, kt2) * 8 + (c16 & 7);
          unsigned short h = f2bf(v);
          tb[idx] = h; tb[512 + idx] = f2bf(v - bf2f(h));
        }
      }
    }

    // ---- P4: L2 (4 tiles/wave in 2 pairs, K=128) -> H2A frags, B rotated
    #pragma unroll
    for (int pp = 0; pp < 2; ++pp) {
      const int m0 = (w & 3) * 4 + pp * 2, m1 = m0 + 1;   // h2 col tiles 0..15
      const unsigned short* D0 = wsU + OFF_F2*2 + (m0*4)*1024 + l*8;
      const unsigned short* D1 = wsU + OFF_F2*2 + (m1*4)*1024 + l*8;
      bf16x8 nd0h = pp ? *(const bf16x8*)D0 : pd0h;
      bf16x8 nd0l = pp ? *(const bf16x8*)(D0 + 512) : pd0l;
      bf16x8 nd1h = pp ? *(const bf16x8*)D1 : pd1h;
      bf16x8 nd1l = pp ? *(const bf16x8*)(D1 + 512) : pd1l;
      float bb0 = cb2[m0*16 + c16], bb1 = cb2[m1*16 + c16];
      f32x4 a0A = {bb0, bb0, bb0, bb0}, a0B = {0.f, 0.f, 0.f, 0.f};
      f32x4 a1A = {bb1, bb1, bb1, bb1}, a1B = {0.f, 0.f, 0.f, 0.f};
      #pragma unroll
      for (int kt = 0; kt < 4; ++kt) {
        bf16x8 d0h = nd0h, d0l = nd0l, d1h = nd1h, d1l = nd1l;
        if (kt < 3) {
          nd0h = *(const bf16x8*)(D0 + (kt+1)*1024); nd0l = *(const bf16x8*)(D0 + (kt+1)*1024 + 512);
          nd1h = *(const bf16x8*)(D1 + (kt+1)*1024); nd1l = *(const bf16x8*)(D1 + (kt+1)*1024 + 512);
        }
        const unsigned short* ap = H1A + (mt*4 + kt) * 1024 + fslot(l, kt) * 8;
        bf16x8 ah = *(const bf16x8*)ap, al = *(const bf16x8*)(ap + 512);
        a0A = MFMA(ah, d0h, a0A, 0,0,0); a0B = MFMA(ah, d0l, a0B, 0,0,0); a0B = MFMA(al, d0h, a0B, 0,0,0);
        a1A = MFMA(ah, d1h, a1A, 0,0,0); a1B = MFMA(ah, d1l, a1B, 0,0,0); a1B = MFMA(al, d1h, a1B, 0,0,0);
      }
      #pragma unroll
      for (int t2 = 0; t2 < 2; ++t2) {
        int nt = m0 + t2;
        int kt2 = nt >> 1;
        int sb = 16 * ((2*nt + (c16 >> 3)) & 3);
        unsigned short* tb = H2A + (mt*8 + kt2) * 1024;
        #pragma unroll
        for (int i = 0; i < 4; ++i) {
          float v = t2 ? fmaxf(a1A[i] + a1B[i], 0.f) : fmaxf(a0A[i] + a0B[i], 0.f);
          int idx = fslot(4*g + i + sb, kt2) * 8 + (c16 & 7);
          unsigned short h = f2bf(v);
          tb[idx] = h; tb[512 + idx] = f2bf(v - bf2f(h));
        }
      }
    }

    // P5 kt0 B-frag prefetch + tail basis load
    bf16x8 p5h = {}, p5l = {};
    if (w < 4) {
      const unsigned short* F3p = wsU + OFF_F3*2 + ((w & 1)*8)*1024 + l*8;
      p5h = *(const bf16x8*)F3p; p5l = *(const bf16x8*)(F3p + 512);
    } else if (w < 6) {
      const unsigned short* FVp = wsU + OFF_FV3*2 + l*8;
      p5h = *(const bf16x8*)FVp; p5l = *(const bf16x8*)(FVp + 512);
    }
    const int f0 = tid * 2;
    float bas[20];
    {
      const float4* bp = (const float4*)((ws + OFF_BASIS) + f0 * 10);
      #pragma unroll
      for (int i = 0; i < 5; ++i) {
        float4 v = bp[i];
        bas[4*i+0] = v.x; bas[4*i+1] = v.y; bas[4*i+2] = v.z; bas[4*i+3] = v.w;
      }
    }
    __syncthreads();   // B3: H2A/HV2A ready

    // ---- P5: V3+L3 via MFMA (unique owners -> plain LDS stores)
    if (w < 4) {        // L3: tile (lmt = w>>1, lnt = w&1), K=256
      const int lmt = w >> 1, lnt = w & 1;
      const unsigned short* F3 = wsU + OFF_F3*2 + (lnt*8)*1024 + l*8;
      f32x4 aA = {0.f, 0.f, 0.f, 0.f}, aB = {0.f, 0.f, 0.f, 0.f};
      bf16x8 nbh = p5h, nbl = p5l;
      #pragma unroll
      for (int kt = 0; kt < 8; ++kt) {
        bf16x8 bh = nbh, bl = nbl;
        if (kt < 7) {
          nbh = *(const bf16x8*)(F3 + (kt+1)*1024); nbl = *(const bf16x8*)(F3 + (kt+1)*1024 + 512);
        }
        const unsigned short* ap = H2A + (lmt*8 + kt) * 1024 + fslot(l, kt) * 8;
        bf16x8 ah = *(const bf16x8*)ap, al = *(const bf16x8*)(ap + 512);
        aA = MFMA(ah, bh, aA, 0,0,0); aB = MFMA(ah, bl, aB, 0,0,0); aB = MFMA(al, bh, aB, 0,0,0);
      }
      #pragma unroll
      for (int i = 0; i < 4; ++i) {
        int r = lmt*16 + 4*g + i, c = lnt*16 + c16;
        if (c < 20) cpbuf[r*20 + c] = aA[i] + aB[i];
      }
    } else if (w < 6) { // V3: tile (vmt = w-4), K=128
      const int vmt = w - 4;
      const unsigned short* FV = wsU + OFF_FV3*2 + l*8;
      f32x4 aA = {0.f, 0.f, 0.f, 0.f}, aB = {0.f, 0.f, 0.f, 0.f};
      #pragma unroll
      for (int kt = 0; kt < 4; ++kt) {
        bf16x8 bh = kt ? *(const bf16x8*)(FV + kt*1024) : p5h;
        bf16x8 bl = kt ? *(const bf16x8*)(FV + kt*1024 + 512) : p5l;
        const unsigned short* ap = HV2A + (vmt*4 + kt) * 1024 + fslot(l, kt) * 8;
        bf16x8 ah = *(const bf16x8*)ap, al = *(const bf16x8*)(ap + 512);
        aA = MFMA(ah, bh, aA, 0,0,0); aB = MFMA(ah, bl, aB, 0,0,0); aB = MFMA(al, bh, aB, 0,0,0);
      }
      #pragma unroll
      for (int i = 0; i < 4; ++i) {
        int r = vmt*16 + 4*g + i;
        if (c16 < 10) vbuf[r*10 + c16] = aA[i] + aB[i];
      }
    }
    __syncthreads();   // B4: vbuf(logits) + cpbuf(cp sums) ready

    // ---- P6: softmax + wm (tid<32, one row each)
    if (tid < 32) {
      float lg[10]; float m = -1e30f;
      #pragma unroll
      for (int j = 0; j < 10; ++j) { lg[j] = vbuf[tid*10 + j] + wb3[j]; m = fmaxf(m, lg[j]); }
      float s = 0.f;
      #pragma unroll
      for (int j = 0; j < 10; ++j) { float e = expf(lg[j] - m); lg[j] = e; s += e; }
      float inv = __builtin_amdgcn_rcpf(s);
      #pragma unroll
      for (int j = 0; j < 10; ++j) vbuf[tid*10 + j] = lg[j] * inv;
      #pragma unroll
      for (int p = 0; p < 10; ++p) {
        float s0 = cpbuf[tid*20 + 2*p]     + cb3[2*p];
        float s1 = cpbuf[tid*20 + 2*p + 1] + cb3[2*p + 1];
        float cm = 0.5f * (tanhf(s0) + tanhf(s1));
        cpbuf[tid*20 + p] = vbuf[tid*10 + p] * cm;
      }
    }
    __syncthreads();   // B5: w in vbuf[.][0..10), wm in cpbuf[.*20 + 0..10)

    // ---- next-tile x prefetch (before the store phase; hides HBM latency)
    if (tile == 0) {
      const float4* xg = (const float4*)(x + ((size_t)blockIdx.x * 64 + 32 + xr) * 128 + xk8 * 8);
      xv0 = xg[0]; xv1 = xg[1];
    }

    // ---- P7: combine + output. thread = 2 consecutive f-cols x 32 rows.
    for (int rr = 0; rr < 32; ++rr) {
      float wv[10], wm[10];
      #pragma unroll
      for (int p = 0; p < 10; p += 2) {
        float2 a = *(const float2*)(vbuf + rr*10 + p);
        wv[p] = a.x; wv[p+1] = a.y;
        float2 b = *(const float2*)(cpbuf + rr*20 + p);
        wm[p] = b.x; wm[p+1] = b.y;
      }
      float n0 = 0.f, d0 = EPS, n1 = 0.f, d1 = EPS;
      #pragma unroll
      for (int p = 0; p < 10; ++p) {
        n0 = fmaf(bas[p],      wm[p], n0);
        d0 = fmaf(bas[p],      wv[p], d0);
        n1 = fmaf(bas[10 + p], wm[p], n1);
        d1 = fmaf(bas[10 + p], wv[p], d1);
      }
      float2 o;
      o.x = n0 * __builtin_amdgcn_rcpf(d0);
      o.y = n1 * __builtin_amdgcn_rcpf(d1);
      *(float2*)(out + (size_t)(b0 + rr) * 1024 + f0) = o;
    }
  }
}

// ---------------------------------------------------------------------------
extern "C" void kernel_launch(void* const* d_in, const int* in_sizes, int n_in,
                              void* d_out, int out_size, void* d_ws, size_t ws_size,
                              hipStream_t stream)
{
  const float* x   = (const float*)d_in[0];
  const float* cw1 = (const float*)d_in[1];
  const float* cb1 = (const float*)d_in[2];
  const float* cw2 = (const float*)d_in[3];
  const float* cb2 = (const float*)d_in[4];
  const float* cw3 = (const float*)d_in[5];
  const float* cb3 = (const float*)d_in[6];
  const float* ww1 = (const float*)d_in[7];
  const float* wb1 = (const float*)d_in[8];
  const float* ww2 = (const float*)d_in[9];
  const float* wb2 = (const float*)d_in[10];
  const float* ww3 = (const float*)d_in[11];
  const float* wb3 = (const float*)d_in[12];
  float* ws  = (float*)d_ws;
  float* out = (float*)d_out;

  prep_kernel<<<41, 256, 0, stream>>>(cw1, cw2, cw3, ww1, ww2, ww3, ws);
  fused_kernel<<<256, 512, 0, stream>>>(x, cb1, cb2, cb3, wb1, wb2, wb3, ws, out);
}

// Round 14
// 37.720 us; speedup vs baseline: 4.3200x; 1.2912x over previous
//
#include <hip/hip_runtime.h>
#include <math.h>

#define EPS 1e-8f

typedef __attribute__((ext_vector_type(8))) short bf16x8;
typedef __attribute__((ext_vector_type(4))) float f32x4;

// ---- ws layout (FLOAT units). frag tile = 1024 bf16 (hi 512 + lo 512) = 512 floats.
#define OFF_F1    0        // L1  cw1 [8 nt][4 kt]
#define OFF_FV1   16384    // V1  ww1 [4][4]
#define OFF_F2    24576    // L2  cw2 [16][4]
#define OFF_FV2   57344    // V2  ww2 [8][2]
#define OFF_F3    65536    // L3  cw3 [2][8]  (20 rows padded to 32)
#define OFF_FV3   73728    // V3  ww3 [1][4]  (10 rows padded to 16)
#define OFF_BASIS 75776    // [1024][10] fp32

__device__ __forceinline__ unsigned short f2bf(float f){
  unsigned u = __float_as_uint(f);
  return (unsigned short)((u + 0x7fffu + ((u >> 16) & 1u)) >> 16);
}
__device__ __forceinline__ float bf2f(unsigned short h){
  return __uint_as_float(((unsigned)h) << 16);
}
__device__ __forceinline__ int fslot(int s, int kt){
  return s ^ kt ^ (((s >> 4) & 1) << 2);
}

// ---------------------------------------------------------------------------
// prep: B-fragment hi/lo bf16 planes for all six layers + fp32 basis.
// ---------------------------------------------------------------------------
__global__ __launch_bounds__(256) void prep_kernel(
    const float* __restrict__ cw1, const float* __restrict__ cw2, const float* __restrict__ cw3,
    const float* __restrict__ ww1, const float* __restrict__ ww2, const float* __restrict__ ww3,
    float* __restrict__ ws)
{
  int id = blockIdx.x * 256 + threadIdx.x;
  unsigned short* wsU = (unsigned short*)ws;
  if (id < 9472) {
    int t = id >> 6, s = id & 63;
    const float* W; int K, N, tloc, dstF, ktbits;
    if (t < 32)       { W = cw1; K = 128; N = 128; tloc = t;       dstF = OFF_F1;  ktbits = 2; }
    else if (t < 48)  { W = ww1; K = 128; N = 64;  tloc = t - 32;  dstF = OFF_FV1; ktbits = 2; }
    else if (t < 112) { W = cw2; K = 128; N = 256; tloc = t - 48;  dstF = OFF_F2;  ktbits = 2; }
    else if (t < 128) { W = ww2; K = 64;  N = 128; tloc = t - 112; dstF = OFF_FV2; ktbits = 1; }
    else if (t < 144) { W = cw3; K = 256; N = 20;  tloc = t - 128; dstF = OFF_F3;  ktbits = 3; }
    else              { W = ww3; K = 128; N = 10;  tloc = t - 144; dstF = OFF_FV3; ktbits = 2; }
    int kt = tloc & ((1 << ktbits) - 1);
    int nt = tloc >> ktbits;
    int row = nt * 16 + (s & 15);
    int kb  = kt * 32 + 8 * (s >> 4);
    bf16x8 hv, lv;
    #pragma unroll
    for (int j = 0; j < 8; ++j) {
      float v = (row < N) ? W[row * K + kb + j] : 0.f;
      unsigned short h = f2bf(v);
      hv[j] = (short)h;
      lv[j] = (short)f2bf(v - bf2f(h));
    }
    unsigned short* dst = wsU + dstF * 2 + tloc * 1024 + s * 8;
    *(bf16x8*)dst = hv;
    *(bf16x8*)(dst + 512) = lv;
    return;
  }
  id -= 9472;
  if (id < 1024) {
    int f = id;
    float tt = (float)f * (1.0f / 1023.0f);
    float v[10]; float s = 0.f;
    #pragma unroll
    for (int p = 0; p < 10; ++p) {
      float d = tt - (float)p * (1.0f / 9.0f);
      float e = expf(-d * d * 50.0f);
      v[p] = e; s += e;
    }
    float inv = 1.0f / (s + EPS);
    #pragma unroll
    for (int p = 0; p < 10; ++p) ws[OFF_BASIS + f*10 + p] = v[p] * inv;
  }
}

#define MFMA __builtin_amdgcn_mfma_f32_16x16x32_bf16

// ---------------------------------------------------------------------------
// Fully fused, all-MFMA MLP (bf16x3) + softmax/tanh tail + combine.
// 32 rows/block, 512 threads (8 waves), grid 512 (2 blocks/CU) — the r11
// verified structure. P7 combine: thread half = row half, 4 consecutive
// f-cols per thread -> halved LDS reads, float4 coalesced stores.
// ---------------------------------------------------------------------------
__global__ __launch_bounds__(512, 4) void fused_kernel(
    const float* __restrict__ x,
    const float* __restrict__ cb1, const float* __restrict__ cb2, const float* __restrict__ cb3,
    const float* __restrict__ wb1, const float* __restrict__ wb2, const float* __restrict__ wb3,
    const float* __restrict__ ws, float* __restrict__ out)
{
  __shared__ unsigned short H2A[16384];   // h2 A-frags [2 mt][8 kt]; [0..8192) aliases XA
  __shared__ unsigned short H1A[8192];    // h1 A-frags [2 mt][4 kt]
  __shared__ unsigned short HV1A[4096];   // hv1 A-frags [2 mt][2 kt]
  __shared__ unsigned short HV2A[8192];   // hv2 A-frags [2 mt][4 kt]
  __shared__ float vbuf[320];             // logits -> softmax w [32][10]
  __shared__ float cpbuf[640];            // cp sums -> wm [32][20]

  const int tid = threadIdx.x;
  const int l   = tid & 63;
  const int w   = tid >> 6;     // 0..7
  const int g   = l >> 4;       // 0..3
  const int c16 = l & 15;
  const int b0  = blockIdx.x * 32;
  unsigned short* XA = H2A;     // x A-frags [2 mt][4 kt], dead after B2
  const unsigned short* wsU = (const unsigned short*)ws;

  // ---- P0: load x, split hi/lo, write XA frags
  {
    int r = tid >> 4, k8 = tid & 15;
    const float4* xg = (const float4*)(x + (size_t)(b0 + r) * 128 + k8 * 8);
    float4 v0 = xg[0], v1 = xg[1];
    float xv[8] = {v0.x, v0.y, v0.z, v0.w, v1.x, v1.y, v1.z, v1.w};
    bf16x8 hv, lv;
    #pragma unroll
    for (int j = 0; j < 8; ++j) {
      unsigned short h = f2bf(xv[j]);
      hv[j] = (short)h;
      lv[j] = (short)f2bf(xv[j] - bf2f(h));
    }
    int kt = k8 >> 2;
    int tile = (r >> 4) * 4 + kt;
    int s = (r & 15) + 16 * (k8 & 3);
    unsigned short* dst = XA + tile * 1024 + fslot(s, kt) * 8;
    *(bf16x8*)dst = hv;
    *(bf16x8*)(dst + 512) = lv;
  }

  // P1P2 pointers + kt0 B-frag prefetch (global, legal before barrier)
  const int mt  = w >> 2;            // row tile 0..1
  const int ntv = w & 3;             // V1 col tile
  const int nt0 = (w & 3) * 2, nt1 = nt0 + 1;  // L1 col tiles
  const unsigned short* BV  = wsU + OFF_FV1*2 + (ntv*4)*1024 + l*8;
  const unsigned short* BL0 = wsU + OFF_F1*2  + (nt0*4)*1024 + l*8;
  const unsigned short* BL1 = wsU + OFF_F1*2  + (nt1*4)*1024 + l*8;
  bf16x8 nvh = *(const bf16x8*)BV;        bf16x8 nvl = *(const bf16x8*)(BV + 512);
  bf16x8 n0h = *(const bf16x8*)BL0;       bf16x8 n0l = *(const bf16x8*)(BL0 + 512);
  bf16x8 n1h = *(const bf16x8*)BL1;       bf16x8 n1l = *(const bf16x8*)(BL1 + 512);

  __syncthreads();   // B1: XA ready

  // ---- P1P2: V1 (1 tile) + L1 (2 tiles) fused over kt, B rotated
  {
    float bv  = wb1[ntv*16 + c16];
    float bl0 = cb1[nt0*16 + c16], bl1 = cb1[nt1*16 + c16];
    f32x4 aVA = {bv, bv, bv, bv},     aVB = {0.f, 0.f, 0.f, 0.f};
    f32x4 aL0A = {bl0, bl0, bl0, bl0}, aL0B = {0.f, 0.f, 0.f, 0.f};
    f32x4 aL1A = {bl1, bl1, bl1, bl1}, aL1B = {0.f, 0.f, 0.f, 0.f};
    #pragma unroll
    for (int kt = 0; kt < 4; ++kt) {
      bf16x8 vh = nvh, vl = nvl, b0h_ = n0h, b0l_ = n0l, b1h_ = n1h, b1l_ = n1l;
      if (kt < 3) {
        nvh = *(const bf16x8*)(BV  + (kt+1)*1024); nvl = *(const bf16x8*)(BV  + (kt+1)*1024 + 512);
        n0h = *(const bf16x8*)(BL0 + (kt+1)*1024); n0l = *(const bf16x8*)(BL0 + (kt+1)*1024 + 512);
        n1h = *(const bf16x8*)(BL1 + (kt+1)*1024); n1l = *(const bf16x8*)(BL1 + (kt+1)*1024 + 512);
      }
      const unsigned short* ap = XA + (mt*4 + kt) * 1024 + fslot(l, kt) * 8;
      bf16x8 ah = *(const bf16x8*)ap;
      bf16x8 al = *(const bf16x8*)(ap + 512);
      aVA = MFMA(ah, vh, aVA, 0,0,0);   aVB = MFMA(ah, vl, aVB, 0,0,0);   aVB = MFMA(al, vh, aVB, 0,0,0);
      aL0A = MFMA(ah, b0h_, aL0A, 0,0,0); aL0B = MFMA(ah, b0l_, aL0B, 0,0,0); aL0B = MFMA(al, b0h_, aL0B, 0,0,0);
      aL1A = MFMA(ah, b1h_, aL1A, 0,0,0); aL1B = MFMA(ah, b1l_, aL1B, 0,0,0); aL1B = MFMA(al, b1h_, aL1B, 0,0,0);
    }
    // V1 epilogue -> HV1A (hv1 width 64)
    {
      int kt2 = ntv >> 1;
      int sb = 16 * ((2*ntv + (c16 >> 3)) & 3);
      unsigned short* tb = HV1A + (mt*2 + kt2) * 1024;
      #pragma unroll
      for (int i = 0; i < 4; ++i) {
        float v = fmaxf(aVA[i] + aVB[i], 0.f);
        int idx = fslot(4*g + i + sb, kt2) * 8 + (c16 & 7);
        unsigned short h = f2bf(v);
        tb[idx] = h; tb[512 + idx] = f2bf(v - bf2f(h));
      }
    }
    // L1 epilogue -> H1A (h1 width 128)
    #pragma unroll
    for (int t2 = 0; t2 < 2; ++t2) {
      int nt = nt0 + t2;
      int kt2 = nt >> 1;
      int sb = 16 * ((2*nt + (c16 >> 3)) & 3);
      unsigned short* tb = H1A + (mt*4 + kt2) * 1024;
      #pragma unroll
      for (int i = 0; i < 4; ++i) {
        float v = t2 ? fmaxf(aL1A[i] + aL1B[i], 0.f) : fmaxf(aL0A[i] + aL0B[i], 0.f);
        int idx = fslot(4*g + i + sb, kt2) * 8 + (c16 & 7);
        unsigned short h = f2bf(v);
        tb[idx] = h; tb[512 + idx] = f2bf(v - bf2f(h));
      }
    }
  }

  // P3 B-frag preloads (V2: 2 tiles x 2 kt), issued before the barrier
  const int v0t = (w & 3) * 2, v1t = v0t + 1;   // hv2 col tiles 0..7
  const unsigned short* C0 = wsU + OFF_FV2*2 + (v0t*2)*1024 + l*8;
  const unsigned short* C1 = wsU + OFF_FV2*2 + (v1t*2)*1024 + l*8;
  bf16x8 c0h0 = *(const bf16x8*)C0;          bf16x8 c0l0 = *(const bf16x8*)(C0 + 512);
  bf16x8 c0h1 = *(const bf16x8*)(C0 + 1024); bf16x8 c0l1 = *(const bf16x8*)(C0 + 1536);
  bf16x8 c1h0 = *(const bf16x8*)C1;          bf16x8 c1l0 = *(const bf16x8*)(C1 + 512);
  bf16x8 c1h1 = *(const bf16x8*)(C1 + 1024); bf16x8 c1l1 = *(const bf16x8*)(C1 + 1536);

  // P4 pp=0 kt0 B-frag prefetch (global, read-only -> safe before barrier)
  const int m0p = (w & 3) * 4, m1p = m0p + 1;
  const unsigned short* D0p = wsU + OFF_F2*2 + (m0p*4)*1024 + l*8;
  const unsigned short* D1p = wsU + OFF_F2*2 + (m1p*4)*1024 + l*8;
  bf16x8 pd0h = *(const bf16x8*)D0p, pd0l = *(const bf16x8*)(D0p + 512);
  bf16x8 pd1h = *(const bf16x8*)D1p, pd1l = *(const bf16x8*)(D1p + 512);

  __syncthreads();   // B2: H1A/HV1A ready, XA dead

  // ---- P3: V2 (2 tiles/wave, K=64) -> HV2A frags
  {
    float bb0 = wb2[v0t*16 + c16], bb1 = wb2[v1t*16 + c16];
    f32x4 a0A = {bb0, bb0, bb0, bb0}, a0B = {0.f, 0.f, 0.f, 0.f};
    f32x4 a1A = {bb1, bb1, bb1, bb1}, a1B = {0.f, 0.f, 0.f, 0.f};
    {
      const unsigned short* ap = HV1A + (mt*2 + 0) * 1024 + fslot(l, 0) * 8;
      bf16x8 ah = *(const bf16x8*)ap, al = *(const bf16x8*)(ap + 512);
      a0A = MFMA(ah, c0h0, a0A, 0,0,0); a0B = MFMA(ah, c0l0, a0B, 0,0,0); a0B = MFMA(al, c0h0, a0B, 0,0,0);
      a1A = MFMA(ah, c1h0, a1A, 0,0,0); a1B = MFMA(ah, c1l0, a1B, 0,0,0); a1B = MFMA(al, c1h0, a1B, 0,0,0);
    }
    {
      const unsigned short* ap = HV1A + (mt*2 + 1) * 1024 + fslot(l, 1) * 8;
      bf16x8 ah = *(const bf16x8*)ap, al = *(const bf16x8*)(ap + 512);
      a0A = MFMA(ah, c0h1, a0A, 0,0,0); a0B = MFMA(ah, c0l1, a0B, 0,0,0); a0B = MFMA(al, c0h1, a0B, 0,0,0);
      a1A = MFMA(ah, c1h1, a1A, 0,0,0); a1B = MFMA(ah, c1l1, a1B, 0,0,0); a1B = MFMA(al, c1h1, a1B, 0,0,0);
    }
    #pragma unroll
    for (int t2 = 0; t2 < 2; ++t2) {
      int nt = v0t + t2;
      int kt2 = nt >> 1;
      int sb = 16 * ((2*nt + (c16 >> 3)) & 3);
      unsigned short* tb = HV2A + (mt*4 + kt2) * 1024;
      #pragma unroll
      for (int i = 0; i < 4; ++i) {
        float v = t2 ? fmaxf(a1A[i] + a1B[i], 0.f) : fmaxf(a0A[i] + a0B[i], 0.f);
        int idx = fslot(4*g + i + sb, kt2) * 8 + (c16 & 7);
        unsigned short h = f2bf(v);
        tb[idx] = h; tb[512 + idx] = f2bf(v - bf2f(h));
      }
    }
  }

  // ---- P4: L2 (4 tiles/wave in 2 pairs, K=128) -> H2A frags, B rotated
  #pragma unroll
  for (int pp = 0; pp < 2; ++pp) {
    const int m0 = (w & 3) * 4 + pp * 2, m1 = m0 + 1;   // h2 col tiles 0..15
    const unsigned short* D0 = wsU + OFF_F2*2 + (m0*4)*1024 + l*8;
    const unsigned short* D1 = wsU + OFF_F2*2 + (m1*4)*1024 + l*8;
    bf16x8 nd0h = pp ? *(const bf16x8*)D0 : pd0h;
    bf16x8 nd0l = pp ? *(const bf16x8*)(D0 + 512) : pd0l;
    bf16x8 nd1h = pp ? *(const bf16x8*)D1 : pd1h;
    bf16x8 nd1l = pp ? *(const bf16x8*)(D1 + 512) : pd1l;
    float bb0 = cb2[m0*16 + c16], bb1 = cb2[m1*16 + c16];
    f32x4 a0A = {bb0, bb0, bb0, bb0}, a0B = {0.f, 0.f, 0.f, 0.f};
    f32x4 a1A = {bb1, bb1, bb1, bb1}, a1B = {0.f, 0.f, 0.f, 0.f};
    #pragma unroll
    for (int kt = 0; kt < 4; ++kt) {
      bf16x8 d0h = nd0h, d0l = nd0l, d1h = nd1h, d1l = nd1l;
      if (kt < 3) {
        nd0h = *(const bf16x8*)(D0 + (kt+1)*1024); nd0l = *(const bf16x8*)(D0 + (kt+1)*1024 + 512);
        nd1h = *(const bf16x8*)(D1 + (kt+1)*1024); nd1l = *(const bf16x8*)(D1 + (kt+1)*1024 + 512);
      }
      const unsigned short* ap = H1A + (mt*4 + kt) * 1024 + fslot(l, kt) * 8;
      bf16x8 ah = *(const bf16x8*)ap, al = *(const bf16x8*)(ap + 512);
      a0A = MFMA(ah, d0h, a0A, 0,0,0); a0B = MFMA(ah, d0l, a0B, 0,0,0); a0B = MFMA(al, d0h, a0B, 0,0,0);
      a1A = MFMA(ah, d1h, a1A, 0,0,0); a1B = MFMA(ah, d1l, a1B, 0,0,0); a1B = MFMA(al, d1h, a1B, 0,0,0);
    }
    #pragma unroll
    for (int t2 = 0; t2 < 2; ++t2) {
      int nt = m0 + t2;
      int kt2 = nt >> 1;
      int sb = 16 * ((2*nt + (c16 >> 3)) & 3);
      unsigned short* tb = H2A + (mt*8 + kt2) * 1024;
      #pragma unroll
      for (int i = 0; i < 4; ++i) {
        float v = t2 ? fmaxf(a1A[i] + a1B[i], 0.f) : fmaxf(a0A[i] + a0B[i], 0.f);
        int idx = fslot(4*g + i + sb, kt2) * 8 + (c16 & 7);
        unsigned short h = f2bf(v);
        tb[idx] = h; tb[512 + idx] = f2bf(v - bf2f(h));
      }
    }
  }

  // P5 kt0 B-frag prefetch + tail basis hoist (global, safe before barrier)
  bf16x8 p5h = {}, p5l = {};
  if (w < 4) {
    const unsigned short* F3p = wsU + OFF_F3*2 + ((w & 1)*8)*1024 + l*8;
    p5h = *(const bf16x8*)F3p; p5l = *(const bf16x8*)(F3p + 512);
  } else if (w < 6) {
    const unsigned short* FVp = wsU + OFF_FV3*2 + l*8;
    p5h = *(const bf16x8*)FVp; p5l = *(const bf16x8*)(FVp + 512);
  }
  // P7 geometry: half = row half, 4 consecutive f-cols per thread.
  const int half  = tid >> 8;            // 0: rows 0-15, 1: rows 16-31
  const int rbase = half * 16;
  const int f0    = (tid & 255) * 4;
  float bas[4][10];
  {
    const float* BAS = ws + OFF_BASIS;
    #pragma unroll
    for (int i = 0; i < 4; ++i) {
      const float2* bp = (const float2*)(BAS + (f0 + i) * 10);
      #pragma unroll
      for (int p = 0; p < 5; ++p) { float2 v = bp[p]; bas[i][2*p] = v.x; bas[i][2*p+1] = v.y; }
    }
  }
  __syncthreads();   // B3: H2A/HV2A ready

  // ---- P5: V3+L3 via MFMA (unique owners -> plain LDS stores)
  if (w < 4) {        // L3: tile (lmt = w>>1, lnt = w&1), K=256
    const int lmt = w >> 1, lnt = w & 1;
    const unsigned short* F3 = wsU + OFF_F3*2 + (lnt*8)*1024 + l*8;
    f32x4 aA = {0.f, 0.f, 0.f, 0.f}, aB = {0.f, 0.f, 0.f, 0.f};
    bf16x8 nbh = p5h, nbl = p5l;
    #pragma unroll
    for (int kt = 0; kt < 8; ++kt) {
      bf16x8 bh = nbh, bl = nbl;
      if (kt < 7) {
        nbh = *(const bf16x8*)(F3 + (kt+1)*1024); nbl = *(const bf16x8*)(F3 + (kt+1)*1024 + 512);
      }
      const unsigned short* ap = H2A + (lmt*8 + kt) * 1024 + fslot(l, kt) * 8;
      bf16x8 ah = *(const bf16x8*)ap, al = *(const bf16x8*)(ap + 512);
      aA = MFMA(ah, bh, aA, 0,0,0); aB = MFMA(ah, bl, aB, 0,0,0); aB = MFMA(al, bh, aB, 0,0,0);
    }
    #pragma unroll
    for (int i = 0; i < 4; ++i) {
      int r = lmt*16 + 4*g + i, c = lnt*16 + c16;
      if (c < 20) cpbuf[r*20 + c] = aA[i] + aB[i];
    }
  } else if (w < 6) { // V3: tile (vmt = w-4), K=128
    const int vmt = w - 4;
    const unsigned short* FV = wsU + OFF_FV3*2 + l*8;
    f32x4 aA = {0.f, 0.f, 0.f, 0.f}, aB = {0.f, 0.f, 0.f, 0.f};
    #pragma unroll
    for (int kt = 0; kt < 4; ++kt) {
      bf16x8 bh = kt ? *(const bf16x8*)(FV + kt*1024) : p5h;
      bf16x8 bl = kt ? *(const bf16x8*)(FV + kt*1024 + 512) : p5l;
      const unsigned short* ap = HV2A + (vmt*4 + kt) * 1024 + fslot(l, kt) * 8;
      bf16x8 ah = *(const bf16x8*)ap, al = *(const bf16x8*)(ap + 512);
      aA = MFMA(ah, bh, aA, 0,0,0); aB = MFMA(ah, bl, aB, 0,0,0); aB = MFMA(al, bh, aB, 0,0,0);
    }
    #pragma unroll
    for (int i = 0; i < 4; ++i) {
      int r = vmt*16 + 4*g + i;
      if (c16 < 10) vbuf[r*10 + c16] = aA[i] + aB[i];
    }
  }
  __syncthreads();   // B4: vbuf(logits) + cpbuf(cp sums) ready

  // ---- P6: softmax + wm (tid<32, one row each)
  if (tid < 32) {
    float lg[10]; float m = -1e30f;
    #pragma unroll
    for (int j = 0; j < 10; ++j) { lg[j] = vbuf[tid*10 + j] + wb3[j]; m = fmaxf(m, lg[j]); }
    float s = 0.f;
    #pragma unroll
    for (int j = 0; j < 10; ++j) { float e = expf(lg[j] - m); lg[j] = e; s += e; }
    float inv = __builtin_amdgcn_rcpf(s);
    #pragma unroll
    for (int j = 0; j < 10; ++j) vbuf[tid*10 + j] = lg[j] * inv;
    #pragma unroll
    for (int p = 0; p < 10; ++p) {
      float s0 = cpbuf[tid*20 + 2*p]     + cb3[2*p];
      float s1 = cpbuf[tid*20 + 2*p + 1] + cb3[2*p + 1];
      float cm = 0.5f * (tanhf(s0) + tanhf(s1));
      cpbuf[tid*20 + p] = vbuf[tid*10 + p] * cm;
    }
  }
  __syncthreads();   // B5: w in vbuf[.][0..10), wm in cpbuf[.*20 + 0..10)

  // ---- P7: combine + output. thread = 4 consecutive f-cols x 16 rows
  // (row half by tid>>8); float4 stores, fully coalesced per 256-thread half.
  for (int rr = 0; rr < 16; ++rr) {
    const int r = rbase + rr;
    float wv[10], wm[10];
    #pragma unroll
    for (int p = 0; p < 10; p += 2) {
      float2 a = *(const float2*)(vbuf + r*10 + p);
      wv[p] = a.x; wv[p+1] = a.y;
      float2 b = *(const float2*)(cpbuf + r*20 + p);
      wm[p] = b.x; wm[p+1] = b.y;
    }
    float4 o;
    float n, d;
    n = 0.f; d = EPS;
    #pragma unroll
    for (int p = 0; p < 10; ++p) { n = fmaf(bas[0][p], wm[p], n); d = fmaf(bas[0][p], wv[p], d); }
    o.x = n * __builtin_amdgcn_rcpf(d);
    n = 0.f; d = EPS;
    #pragma unroll
    for (int p = 0; p < 10; ++p) { n = fmaf(bas[1][p], wm[p], n); d = fmaf(bas[1][p], wv[p], d); }
    o.y = n * __builtin_amdgcn_rcpf(d);
    n = 0.f; d = EPS;
    #pragma unroll
    for (int p = 0; p < 10; ++p) { n = fmaf(bas[2][p], wm[p], n); d = fmaf(bas[2][p], wv[p], d); }
    o.z = n * __builtin_amdgcn_rcpf(d);
    n = 0.f; d = EPS;
    #pragma unroll
    for (int p = 0; p < 10; ++p) { n = fmaf(bas[3][p], wm[p], n); d = fmaf(bas[3][p], wv[p], d); }
    o.w = n * __builtin_amdgcn_rcpf(d);
    *(float4*)(out + (size_t)(b0 + r) * 1024 + f0) = o;
  }
}

// ---------------------------------------------------------------------------
extern "C" void kernel_launch(void* const* d_in, const int* in_sizes, int n_in,
                              void* d_out, int out_size, void* d_ws, size_t ws_size,
                              hipStream_t stream)
{
  const float* x   = (const float*)d_in[0];
  const float* cw1 = (const float*)d_in[1];
  const float* cb1 = (const float*)d_in[2];
  const float* cw2 = (const float*)d_in[3];
  const float* cb2 = (const float*)d_in[4];
  const float* cw3 = (const float*)d_in[5];
  const float* cb3 = (const float*)d_in[6];
  const float* ww1 = (const float*)d_in[7];
  const float* wb1 = (const float*)d_in[8];
  const float* ww2 = (const float*)d_in[9];
  const float* wb2 = (const float*)d_in[10];
  const float* ww3 = (const float*)d_in[11];
  const float* wb3 = (const float*)d_in[12];
  float* ws  = (float*)d_ws;
  float* out = (float*)d_out;

  prep_kernel<<<41, 256, 0, stream>>>(cw1, cw2, cw3, ww1, ww2, ww3, ws);
  fused_kernel<<<512, 512, 0, stream>>>(x, cb1, cb2, cb3, wb1, wb2, wb3, ws, out);
}

// Round 16
// 37.576 us; speedup vs baseline: 4.3366x; 1.0038x over previous
//
#include <hip/hip_runtime.h>
#include <math.h>

#define EPS 1e-8f

typedef __attribute__((ext_vector_type(8))) short bf16x8;
typedef __attribute__((ext_vector_type(4))) float f32x4;

// ---- ws layout (FLOAT units). frag tile = 1024 bf16 (hi 512 + lo 512) = 512 floats.
#define OFF_F1    0        // L1  cw1 [8 nt][4 kt]
#define OFF_FV1   16384    // V1  ww1 [4][4]
#define OFF_F2    24576    // L2  cw2 [16][4]
#define OFF_FV2   57344    // V2  ww2 [8][2]
#define OFF_F3    65536    // L3  cw3 [2][8]  (20 rows padded to 32)
#define OFF_FV3   73728    // V3  ww3 [1][4]  (10 rows padded to 16)
#define OFF_BASIS 75776    // [1024][10] fp32

__device__ __forceinline__ unsigned short f2bf(float f){
  unsigned u = __float_as_uint(f);
  return (unsigned short)((u + 0x7fffu + ((u >> 16) & 1u)) >> 16);
}
__device__ __forceinline__ float bf2f(unsigned short h){
  return __uint_as_float(((unsigned)h) << 16);
}
__device__ __forceinline__ int fslot(int s, int kt){
  return s ^ kt ^ (((s >> 4) & 1) << 2);
}

// ---------------------------------------------------------------------------
// prep: B-fragment hi/lo bf16 planes for all six layers + fp32 basis.
// ---------------------------------------------------------------------------
__global__ __launch_bounds__(256) void prep_kernel(
    const float* __restrict__ cw1, const float* __restrict__ cw2, const float* __restrict__ cw3,
    const float* __restrict__ ww1, const float* __restrict__ ww2, const float* __restrict__ ww3,
    float* __restrict__ ws)
{
  int id = blockIdx.x * 256 + threadIdx.x;
  unsigned short* wsU = (unsigned short*)ws;
  if (id < 9472) {
    int t = id >> 6, s = id & 63;
    const float* W; int K, N, tloc, dstF, ktbits;
    if (t < 32)       { W = cw1; K = 128; N = 128; tloc = t;       dstF = OFF_F1;  ktbits = 2; }
    else if (t < 48)  { W = ww1; K = 128; N = 64;  tloc = t - 32;  dstF = OFF_FV1; ktbits = 2; }
    else if (t < 112) { W = cw2; K = 128; N = 256; tloc = t - 48;  dstF = OFF_F2;  ktbits = 2; }
    else if (t < 128) { W = ww2; K = 64;  N = 128; tloc = t - 112; dstF = OFF_FV2; ktbits = 1; }
    else if (t < 144) { W = cw3; K = 256; N = 20;  tloc = t - 128; dstF = OFF_F3;  ktbits = 3; }
    else              { W = ww3; K = 128; N = 10;  tloc = t - 144; dstF = OFF_FV3; ktbits = 2; }
    int kt = tloc & ((1 << ktbits) - 1);
    int nt = tloc >> ktbits;
    int row = nt * 16 + (s & 15);
    int kb  = kt * 32 + 8 * (s >> 4);
    bf16x8 hv, lv;
    #pragma unroll
    for (int j = 0; j < 8; ++j) {
      float v = (row < N) ? W[row * K + kb + j] : 0.f;
      unsigned short h = f2bf(v);
      hv[j] = (short)h;
      lv[j] = (short)f2bf(v - bf2f(h));
    }
    unsigned short* dst = wsU + dstF * 2 + tloc * 1024 + s * 8;
    *(bf16x8*)dst = hv;
    *(bf16x8*)(dst + 512) = lv;
    return;
  }
  id -= 9472;
  if (id < 1024) {
    int f = id;
    float tt = (float)f * (1.0f / 1023.0f);
    float v[10]; float s = 0.f;
    #pragma unroll
    for (int p = 0; p < 10; ++p) {
      float d = tt - (float)p * (1.0f / 9.0f);
      float e = expf(-d * d * 50.0f);
      v[p] = e; s += e;
    }
    float inv = 1.0f / (s + EPS);
    #pragma unroll
    for (int p = 0; p < 10; ++p) ws[OFF_BASIS + f*10 + p] = v[p] * inv;
  }
}

#define MFMA __builtin_amdgcn_mfma_f32_16x16x32_bf16

// ---------------------------------------------------------------------------
// Fully fused, all-MFMA MLP (bf16x3) + softmax/tanh tail + combine.
// 32 rows/block, 512 threads (8 waves), grid 512 (2 blocks/CU) — the r11
// verified structure. P7 combine: thread half = row half, 4 consecutive
// f-cols per thread -> halved LDS reads, float4 coalesced stores.
// ---------------------------------------------------------------------------
__global__ __launch_bounds__(512, 4) void fused_kernel(
    const float* __restrict__ x,
    const float* __restrict__ cb1, const float* __restrict__ cb2, const float* __restrict__ cb3,
    const float* __restrict__ wb1, const float* __restrict__ wb2, const float* __restrict__ wb3,
    const float* __restrict__ ws, float* __restrict__ out)
{
  __shared__ unsigned short H2A[16384];   // h2 A-frags [2 mt][8 kt]; [0..8192) aliases XA
  __shared__ unsigned short H1A[8192];    // h1 A-frags [2 mt][4 kt]
  __shared__ unsigned short HV1A[4096];   // hv1 A-frags [2 mt][2 kt]
  __shared__ unsigned short HV2A[8192];   // hv2 A-frags [2 mt][4 kt]
  __shared__ float vbuf[320];             // logits -> softmax w [32][10]
  __shared__ float cpbuf[640];            // cp sums -> wm [32][20]

  const int tid = threadIdx.x;
  const int l   = tid & 63;
  const int w   = tid >> 6;     // 0..7
  const int g   = l >> 4;       // 0..3
  const int c16 = l & 15;
  const int b0  = blockIdx.x * 32;
  unsigned short* XA = H2A;     // x A-frags [2 mt][4 kt], dead after B2
  const unsigned short* wsU = (const unsigned short*)ws;

  // ---- P0: load x, split hi/lo, write XA frags
  {
    int r = tid >> 4, k8 = tid & 15;
    const float4* xg = (const float4*)(x + (size_t)(b0 + r) * 128 + k8 * 8);
    float4 v0 = xg[0], v1 = xg[1];
    float xv[8] = {v0.x, v0.y, v0.z, v0.w, v1.x, v1.y, v1.z, v1.w};
    bf16x8 hv, lv;
    #pragma unroll
    for (int j = 0; j < 8; ++j) {
      unsigned short h = f2bf(xv[j]);
      hv[j] = (short)h;
      lv[j] = (short)f2bf(xv[j] - bf2f(h));
    }
    int kt = k8 >> 2;
    int tile = (r >> 4) * 4 + kt;
    int s = (r & 15) + 16 * (k8 & 3);
    unsigned short* dst = XA + tile * 1024 + fslot(s, kt) * 8;
    *(bf16x8*)dst = hv;
    *(bf16x8*)(dst + 512) = lv;
  }

  // P1P2 pointers + kt0 B-frag prefetch (global, legal before barrier)
  const int mt  = w >> 2;            // row tile 0..1
  const int ntv = w & 3;             // V1 col tile
  const int nt0 = (w & 3) * 2, nt1 = nt0 + 1;  // L1 col tiles
  const unsigned short* BV  = wsU + OFF_FV1*2 + (ntv*4)*1024 + l*8;
  const unsigned short* BL0 = wsU + OFF_F1*2  + (nt0*4)*1024 + l*8;
  const unsigned short* BL1 = wsU + OFF_F1*2  + (nt1*4)*1024 + l*8;
  bf16x8 nvh = *(const bf16x8*)BV;        bf16x8 nvl = *(const bf16x8*)(BV + 512);
  bf16x8 n0h = *(const bf16x8*)BL0;       bf16x8 n0l = *(const bf16x8*)(BL0 + 512);
  bf16x8 n1h = *(const bf16x8*)BL1;       bf16x8 n1l = *(const bf16x8*)(BL1 + 512);

  __syncthreads();   // B1: XA ready

  // ---- P1P2: V1 (1 tile) + L1 (2 tiles) fused over kt, B rotated
  {
    float bv  = wb1[ntv*16 + c16];
    float bl0 = cb1[nt0*16 + c16], bl1 = cb1[nt1*16 + c16];
    f32x4 aVA = {bv, bv, bv, bv},     aVB = {0.f, 0.f, 0.f, 0.f};
    f32x4 aL0A = {bl0, bl0, bl0, bl0}, aL0B = {0.f, 0.f, 0.f, 0.f};
    f32x4 aL1A = {bl1, bl1, bl1, bl1}, aL1B = {0.f, 0.f, 0.f, 0.f};
    #pragma unroll
    for (int kt = 0; kt < 4; ++kt) {
      bf16x8 vh = nvh, vl = nvl, b0h_ = n0h, b0l_ = n0l, b1h_ = n1h, b1l_ = n1l;
      if (kt < 3) {
        nvh = *(const bf16x8*)(BV  + (kt+1)*1024); nvl = *(const bf16x8*)(BV  + (kt+1)*1024 + 512);
        n0h = *(const bf16x8*)(BL0 + (kt+1)*1024); n0l = *(const bf16x8*)(BL0 + (kt+1)*1024 + 512);
        n1h = *(const bf16x8*)(BL1 + (kt+1)*1024); n1l = *(const bf16x8*)(BL1 + (kt+1)*1024 + 512);
      }
      const unsigned short* ap = XA + (mt*4 + kt) * 1024 + fslot(l, kt) * 8;
      bf16x8 ah = *(const bf16x8*)ap;
      bf16x8 al = *(const bf16x8*)(ap + 512);
      aVA = MFMA(ah, vh, aVA, 0,0,0);   aVB = MFMA(ah, vl, aVB, 0,0,0);   aVB = MFMA(al, vh, aVB, 0,0,0);
      aL0A = MFMA(ah, b0h_, aL0A, 0,0,0); aL0B = MFMA(ah, b0l_, aL0B, 0,0,0); aL0B = MFMA(al, b0h_, aL0B, 0,0,0);
      aL1A = MFMA(ah, b1h_, aL1A, 0,0,0); aL1B = MFMA(ah, b1l_, aL1B, 0,0,0); aL1B = MFMA(al, b1h_, aL1B, 0,0,0);
    }
    // V1 epilogue -> HV1A (hv1 width 64)
    {
      int kt2 = ntv >> 1;
      int sb = 16 * ((2*ntv + (c16 >> 3)) & 3);
      unsigned short* tb = HV1A + (mt*2 + kt2) * 1024;
      #pragma unroll
      for (int i = 0; i < 4; ++i) {
        float v = fmaxf(aVA[i] + aVB[i], 0.f);
        int idx = fslot(4*g + i + sb, kt2) * 8 + (c16 & 7);
        unsigned short h = f2bf(v);
        tb[idx] = h; tb[512 + idx] = f2bf(v - bf2f(h));
      }
    }
    // L1 epilogue -> H1A (h1 width 128)
    #pragma unroll
    for (int t2 = 0; t2 < 2; ++t2) {
      int nt = nt0 + t2;
      int kt2 = nt >> 1;
      int sb = 16 * ((2*nt + (c16 >> 3)) & 3);
      unsigned short* tb = H1A + (mt*4 + kt2) * 1024;
      #pragma unroll
      for (int i = 0; i < 4; ++i) {
        float v = t2 ? fmaxf(aL1A[i] + aL1B[i], 0.f) : fmaxf(aL0A[i] + aL0B[i], 0.f);
        int idx = fslot(4*g + i + sb, kt2) * 8 + (c16 & 7);
        unsigned short h = f2bf(v);
        tb[idx] = h; tb[512 + idx] = f2bf(v - bf2f(h));
      }
    }
  }

  // P3 B-frag preloads (V2: 2 tiles x 2 kt), issued before the barrier
  const int v0t = (w & 3) * 2, v1t = v0t + 1;   // hv2 col tiles 0..7
  const unsigned short* C0 = wsU + OFF_FV2*2 + (v0t*2)*1024 + l*8;
  const unsigned short* C1 = wsU + OFF_FV2*2 + (v1t*2)*1024 + l*8;
  bf16x8 c0h0 = *(const bf16x8*)C0;          bf16x8 c0l0 = *(const bf16x8*)(C0 + 512);
  bf16x8 c0h1 = *(const bf16x8*)(C0 + 1024); bf16x8 c0l1 = *(const bf16x8*)(C0 + 1536);
  bf16x8 c1h0 = *(const bf16x8*)C1;          bf16x8 c1l0 = *(const bf16x8*)(C1 + 512);
  bf16x8 c1h1 = *(const bf16x8*)(C1 + 1024); bf16x8 c1l1 = *(const bf16x8*)(C1 + 1536);

  // P4 pp=0 kt0 B-frag prefetch (global, read-only -> safe before barrier)
  const int m0p = (w & 3) * 4, m1p = m0p + 1;
  const unsigned short* D0p = wsU + OFF_F2*2 + (m0p*4)*1024 + l*8;
  const unsigned short* D1p = wsU + OFF_F2*2 + (m1p*4)*1024 + l*8;
  bf16x8 pd0h = *(const bf16x8*)D0p, pd0l = *(const bf16x8*)(D0p + 512);
  bf16x8 pd1h = *(const bf16x8*)D1p, pd1l = *(const bf16x8*)(D1p + 512);

  __syncthreads();   // B2: H1A/HV1A ready, XA dead

  // ---- P3: V2 (2 tiles/wave, K=64) -> HV2A frags
  {
    float bb0 = wb2[v0t*16 + c16], bb1 = wb2[v1t*16 + c16];
    f32x4 a0A = {bb0, bb0, bb0, bb0}, a0B = {0.f, 0.f, 0.f, 0.f};
    f32x4 a1A = {bb1, bb1, bb1, bb1}, a1B = {0.f, 0.f, 0.f, 0.f};
    {
      const unsigned short* ap = HV1A + (mt*2 + 0) * 1024 + fslot(l, 0) * 8;
      bf16x8 ah = *(const bf16x8*)ap, al = *(const bf16x8*)(ap + 512);
      a0A = MFMA(ah, c0h0, a0A, 0,0,0); a0B = MFMA(ah, c0l0, a0B, 0,0,0); a0B = MFMA(al, c0h0, a0B, 0,0,0);
      a1A = MFMA(ah, c1h0, a1A, 0,0,0); a1B = MFMA(ah, c1l0, a1B, 0,0,0); a1B = MFMA(al, c1h0, a1B, 0,0,0);
    }
    {
      const unsigned short* ap = HV1A + (mt*2 + 1) * 1024 + fslot(l, 1) * 8;
      bf16x8 ah = *(const bf16x8*)ap, al = *(const bf16x8*)(ap + 512);
      a0A = MFMA(ah, c0h1, a0A, 0,0,0); a0B = MFMA(ah, c0l1, a0B, 0,0,0); a0B = MFMA(al, c0h1, a0B, 0,0,0);
      a1A = MFMA(ah, c1h1, a1A, 0,0,0); a1B = MFMA(ah, c1l1, a1B, 0,0,0); a1B = MFMA(al, c1h1, a1B, 0,0,0);
    }
    #pragma unroll
    for (int t2 = 0; t2 < 2; ++t2) {
      int nt = v0t + t2;
      int kt2 = nt >> 1;
      int sb = 16 * ((2*nt + (c16 >> 3)) & 3);
      unsigned short* tb = HV2A + (mt*4 + kt2) * 1024;
      #pragma unroll
      for (int i = 0; i < 4; ++i) {
        float v = t2 ? fmaxf(a1A[i] + a1B[i], 0.f) : fmaxf(a0A[i] + a0B[i], 0.f);
        int idx = fslot(4*g + i + sb, kt2) * 8 + (c16 & 7);
        unsigned short h = f2bf(v);
        tb[idx] = h; tb[512 + idx] = f2bf(v - bf2f(h));
      }
    }
  }

  // ---- P4: L2 (4 tiles/wave in 2 pairs, K=128) -> H2A frags, B rotated
  #pragma unroll
  for (int pp = 0; pp < 2; ++pp) {
    const int m0 = (w & 3) * 4 + pp * 2, m1 = m0 + 1;   // h2 col tiles 0..15
    const unsigned short* D0 = wsU + OFF_F2*2 + (m0*4)*1024 + l*8;
    const unsigned short* D1 = wsU + OFF_F2*2 + (m1*4)*1024 + l*8;
    bf16x8 nd0h = pp ? *(const bf16x8*)D0 : pd0h;
    bf16x8 nd0l = pp ? *(const bf16x8*)(D0 + 512) : pd0l;
    bf16x8 nd1h = pp ? *(const bf16x8*)D1 : pd1h;
    bf16x8 nd1l = pp ? *(const bf16x8*)(D1 + 512) : pd1l;
    float bb0 = cb2[m0*16 + c16], bb1 = cb2[m1*16 + c16];
    f32x4 a0A = {bb0, bb0, bb0, bb0}, a0B = {0.f, 0.f, 0.f, 0.f};
    f32x4 a1A = {bb1, bb1, bb1, bb1}, a1B = {0.f, 0.f, 0.f, 0.f};
    #pragma unroll
    for (int kt = 0; kt < 4; ++kt) {
      bf16x8 d0h = nd0h, d0l = nd0l, d1h = nd1h, d1l = nd1l;
      if (kt < 3) {
        nd0h = *(const bf16x8*)(D0 + (kt+1)*1024); nd0l = *(const bf16x8*)(D0 + (kt+1)*1024 + 512);
        nd1h = *(const bf16x8*)(D1 + (kt+1)*1024); nd1l = *(const bf16x8*)(D1 + (kt+1)*1024 + 512);
      }
      const unsigned short* ap = H1A + (mt*4 + kt) * 1024 + fslot(l, kt) * 8;
      bf16x8 ah = *(const bf16x8*)ap, al = *(const bf16x8*)(ap + 512);
      a0A = MFMA(ah, d0h, a0A, 0,0,0); a0B = MFMA(ah, d0l, a0B, 0,0,0); a0B = MFMA(al, d0h, a0B, 0,0,0);
      a1A = MFMA(ah, d1h, a1A, 0,0,0); a1B = MFMA(ah, d1l, a1B, 0,0,0); a1B = MFMA(al, d1h, a1B, 0,0,0);
    }
    #pragma unroll
    for (int t2 = 0; t2 < 2; ++t2) {
      int nt = m0 + t2;
      int kt2 = nt >> 1;
      int sb = 16 * ((2*nt + (c16 >> 3)) & 3);
      unsigned short* tb = H2A + (mt*8 + kt2) * 1024;
      #pragma unroll
      for (int i = 0; i < 4; ++i) {
        float v = t2 ? fmaxf(a1A[i] + a1B[i], 0.f) : fmaxf(a0A[i] + a0B[i], 0.f);
        int idx = fslot(4*g + i + sb, kt2) * 8 + (c16 & 7);
        unsigned short h = f2bf(v);
        tb[idx] = h; tb[512 + idx] = f2bf(v - bf2f(h));
      }
    }
  }

  // P5 kt0 B-frag prefetch + tail basis hoist (global, safe before barrier)
  bf16x8 p5h = {}, p5l = {};
  if (w < 4) {
    const unsigned short* F3p = wsU + OFF_F3*2 + ((w & 1)*8)*1024 + l*8;
    p5h = *(const bf16x8*)F3p; p5l = *(const bf16x8*)(F3p + 512);
  } else if (w < 6) {
    const unsigned short* FVp = wsU + OFF_FV3*2 + l*8;
    p5h = *(const bf16x8*)FVp; p5l = *(const bf16x8*)(FVp + 512);
  }
  // P7 geometry: half = row half, 4 consecutive f-cols per thread.
  const int half  = tid >> 8;            // 0: rows 0-15, 1: rows 16-31
  const int rbase = half * 16;
  const int f0    = (tid & 255) * 4;
  float bas[4][10];
  {
    const float* BAS = ws + OFF_BASIS;
    #pragma unroll
    for (int i = 0; i < 4; ++i) {
      const float2* bp = (const float2*)(BAS + (f0 + i) * 10);
      #pragma unroll
      for (int p = 0; p < 5; ++p) { float2 v = bp[p]; bas[i][2*p] = v.x; bas[i][2*p+1] = v.y; }
    }
  }
  __syncthreads();   // B3: H2A/HV2A ready

  // ---- P5: V3+L3 via MFMA (unique owners -> plain LDS stores)
  if (w < 4) {        // L3: tile (lmt = w>>1, lnt = w&1), K=256
    const int lmt = w >> 1, lnt = w & 1;
    const unsigned short* F3 = wsU + OFF_F3*2 + (lnt*8)*1024 + l*8;
    f32x4 aA = {0.f, 0.f, 0.f, 0.f}, aB = {0.f, 0.f, 0.f, 0.f};
    bf16x8 nbh = p5h, nbl = p5l;
    #pragma unroll
    for (int kt = 0; kt < 8; ++kt) {
      bf16x8 bh = nbh, bl = nbl;
      if (kt < 7) {
        nbh = *(const bf16x8*)(F3 + (kt+1)*1024); nbl = *(const bf16x8*)(F3 + (kt+1)*1024 + 512);
      }
      const unsigned short* ap = H2A + (lmt*8 + kt) * 1024 + fslot(l, kt) * 8;
      bf16x8 ah = *(const bf16x8*)ap, al = *(const bf16x8*)(ap + 512);
      aA = MFMA(ah, bh, aA, 0,0,0); aB = MFMA(ah, bl, aB, 0,0,0); aB = MFMA(al, bh, aB, 0,0,0);
    }
    #pragma unroll
    for (int i = 0; i < 4; ++i) {
      int r = lmt*16 + 4*g + i, c = lnt*16 + c16;
      if (c < 20) cpbuf[r*20 + c] = aA[i] + aB[i];
    }
  } else if (w < 6) { // V3: tile (vmt = w-4), K=128
    const int vmt = w - 4;
    const unsigned short* FV = wsU + OFF_FV3*2 + l*8;
    f32x4 aA = {0.f, 0.f, 0.f, 0.f}, aB = {0.f, 0.f, 0.f, 0.f};
    #pragma unroll
    for (int kt = 0; kt < 4; ++kt) {
      bf16x8 bh = kt ? *(const bf16x8*)(FV + kt*1024) : p5h;
      bf16x8 bl = kt ? *(const bf16x8*)(FV + kt*1024 + 512) : p5l;
      const unsigned short* ap = HV2A + (vmt*4 + kt) * 1024 + fslot(l, kt) * 8;
      bf16x8 ah = *(const bf16x8*)ap, al = *(const bf16x8*)(ap + 512);
      aA = MFMA(ah, bh, aA, 0,0,0); aB = MFMA(ah, bl, aB, 0,0,0); aB = MFMA(al, bh, aB, 0,0,0);
    }
    #pragma unroll
    for (int i = 0; i < 4; ++i) {
      int r = vmt*16 + 4*g + i;
      if (c16 < 10) vbuf[r*10 + c16] = aA[i] + aB[i];
    }
  }
  __syncthreads();   // B4: vbuf(logits) + cpbuf(cp sums) ready

  // ---- P6: softmax + wm (tid<32, one row each)
  if (tid < 32) {
    float lg[10]; float m = -1e30f;
    #pragma unroll
    for (int j = 0; j < 10; ++j) { lg[j] = vbuf[tid*10 + j] + wb3[j]; m = fmaxf(m, lg[j]); }
    float s = 0.f;
    #pragma unroll
    for (int j = 0; j < 10; ++j) { float e = expf(lg[j] - m); lg[j] = e; s += e; }
    float inv = __builtin_amdgcn_rcpf(s);
    #pragma unroll
    for (int j = 0; j < 10; ++j) vbuf[tid*10 + j] = lg[j] * inv;
    #pragma unroll
    for (int p = 0; p < 10; ++p) {
      float s0 = cpbuf[tid*20 + 2*p]     + cb3[2*p];
      float s1 = cpbuf[tid*20 + 2*p + 1] + cb3[2*p + 1];
      float cm = 0.5f * (tanhf(s0) + tanhf(s1));
      cpbuf[tid*20 + p] = vbuf[tid*10 + p] * cm;
    }
  }
  __syncthreads();   // B5: w in vbuf[.][0..10), wm in cpbuf[.*20 + 0..10)

  // ---- P7: combine + output. thread = 4 consecutive f-cols x 16 rows
  // (row half by tid>>8); float4 stores, fully coalesced per 256-thread half.
  for (int rr = 0; rr < 16; ++rr) {
    const int r = rbase + rr;
    float wv[10], wm[10];
    #pragma unroll
    for (int p = 0; p < 10; p += 2) {
      float2 a = *(const float2*)(vbuf + r*10 + p);
      wv[p] = a.x; wv[p+1] = a.y;
      float2 b = *(const float2*)(cpbuf + r*20 + p);
      wm[p] = b.x; wm[p+1] = b.y;
    }
    float4 o;
    float n, d;
    n = 0.f; d = EPS;
    #pragma unroll
    for (int p = 0; p < 10; ++p) { n = fmaf(bas[0][p], wm[p], n); d = fmaf(bas[0][p], wv[p], d); }
    o.x = n * __builtin_amdgcn_rcpf(d);
    n = 0.f; d = EPS;
    #pragma unroll
    for (int p = 0; p < 10; ++p) { n = fmaf(bas[1][p], wm[p], n); d = fmaf(bas[1][p], wv[p], d); }
    o.y = n * __builtin_amdgcn_rcpf(d);
    n = 0.f; d = EPS;
    #pragma unroll
    for (int p = 0; p < 10; ++p) { n = fmaf(bas[2][p], wm[p], n); d = fmaf(bas[2][p], wv[p], d); }
    o.z = n * __builtin_amdgcn_rcpf(d);
    n = 0.f; d = EPS;
    #pragma unroll
    for (int p = 0; p < 10; ++p) { n = fmaf(bas[3][p], wm[p], n); d = fmaf(bas[3][p], wv[p], d); }
    o.w = n * __builtin_amdgcn_rcpf(d);
    *(float4*)(out + (size_t)(b0 + r) * 1024 + f0) = o;
  }
}

// ---------------------------------------------------------------------------
extern "C" void kernel_launch(void* const* d_in, const int* in_sizes, int n_in,
                              void* d_out, int out_size, void* d_ws, size_t ws_size,
                              hipStream_t stream)
{
  const float* x   = (const float*)d_in[0];
  const float* cw1 = (const float*)d_in[1];
  const float* cb1 = (const float*)d_in[2];
  const float* cw2 = (const float*)d_in[3];
  const float* cb2 = (const float*)d_in[4];
  const float* cw3 = (const float*)d_in[5];
  const float* cb3 = (const float*)d_in[6];
  const float* ww1 = (const float*)d_in[7];
  const float* wb1 = (const float*)d_in[8];
  const float* ww2 = (const float*)d_in[9];
  const float* wb2 = (const float*)d_in[10];
  const float* ww3 = (const float*)d_in[11];
  const float* wb3 = (const float*)d_in[12];
  float* ws  = (float*)d_ws;
  float* out = (float*)d_out;

  prep_kernel<<<41, 256, 0, stream>>>(cw1, cw2, cw3, ww1, ww2, ww3, ws);
  fused_kernel<<<512, 512, 0, stream>>>(x, cb1, cb2, cb3, wb1, wb2, wb3, ws, out);
}

// Round 18
// 36.611 us; speedup vs baseline: 4.4509x; 1.0264x over previous
//
#include <hip/hip_runtime.h>
#include <math.h>

#define EPS 1e-8f

typedef __attribute__((ext_vector_type(8))) short bf16x8;
typedef __attribute__((ext_vector_type(4))) float f32x4;

// ---- ws layout (FLOAT units). frag tile = 1024 bf16 (hi 512 + lo 512) = 512 floats.
#define OFF_F1    0        // L1  cw1 [8 nt][4 kt]
#define OFF_FV1   16384    // V1  ww1 [4][4]
#define OFF_F2    24576    // L2  cw2 [16][4]
#define OFF_FV2   57344    // V2  ww2 [8][2]
#define OFF_F3    65536    // L3  cw3 [2][8]  (20 rows padded to 32)
#define OFF_FV3   73728    // V3  ww3 [1][4]  (10 rows padded to 16)
#define OFF_BASIS 75776    // [1024][10] fp32

__device__ __forceinline__ unsigned short f2bf(float f){
  unsigned u = __float_as_uint(f);
  return (unsigned short)((u + 0x7fffu + ((u >> 16) & 1u)) >> 16);
}
__device__ __forceinline__ float bf2f(unsigned short h){
  return __uint_as_float(((unsigned)h) << 16);
}
__device__ __forceinline__ int fslot(int s, int kt){
  return s ^ kt ^ (((s >> 4) & 1) << 2);
}

// ---------------------------------------------------------------------------
// prep: B-fragment hi/lo bf16 planes for all six layers + fp32 basis.
// ---------------------------------------------------------------------------
__global__ __launch_bounds__(256) void prep_kernel(
    const float* __restrict__ cw1, const float* __restrict__ cw2, const float* __restrict__ cw3,
    const float* __restrict__ ww1, const float* __restrict__ ww2, const float* __restrict__ ww3,
    float* __restrict__ ws)
{
  int id = blockIdx.x * 256 + threadIdx.x;
  unsigned short* wsU = (unsigned short*)ws;
  if (id < 9472) {
    int t = id >> 6, s = id & 63;
    const float* W; int K, N, tloc, dstF, ktbits;
    if (t < 32)       { W = cw1; K = 128; N = 128; tloc = t;       dstF = OFF_F1;  ktbits = 2; }
    else if (t < 48)  { W = ww1; K = 128; N = 64;  tloc = t - 32;  dstF = OFF_FV1; ktbits = 2; }
    else if (t < 112) { W = cw2; K = 128; N = 256; tloc = t - 48;  dstF = OFF_F2;  ktbits = 2; }
    else if (t < 128) { W = ww2; K = 64;  N = 128; tloc = t - 112; dstF = OFF_FV2; ktbits = 1; }
    else if (t < 144) { W = cw3; K = 256; N = 20;  tloc = t - 128; dstF = OFF_F3;  ktbits = 3; }
    else              { W = ww3; K = 128; N = 10;  tloc = t - 144; dstF = OFF_FV3; ktbits = 2; }
    int kt = tloc & ((1 << ktbits) - 1);
    int nt = tloc >> ktbits;
    int row = nt * 16 + (s & 15);
    int kb  = kt * 32 + 8 * (s >> 4);
    bf16x8 hv, lv;
    #pragma unroll
    for (int j = 0; j < 8; ++j) {
      float v = (row < N) ? W[row * K + kb + j] : 0.f;
      unsigned short h = f2bf(v);
      hv[j] = (short)h;
      lv[j] = (short)f2bf(v - bf2f(h));
    }
    unsigned short* dst = wsU + dstF * 2 + tloc * 1024 + s * 8;
    *(bf16x8*)dst = hv;
    *(bf16x8*)(dst + 512) = lv;
    return;
  }
  id -= 9472;
  if (id < 1024) {
    int f = id;
    float tt = (float)f * (1.0f / 1023.0f);
    float v[10]; float s = 0.f;
    #pragma unroll
    for (int p = 0; p < 10; ++p) {
      float d = tt - (float)p * (1.0f / 9.0f);
      float e = expf(-d * d * 50.0f);
      v[p] = e; s += e;
    }
    float inv = 1.0f / (s + EPS);
    #pragma unroll
    for (int p = 0; p < 10; ++p) ws[OFF_BASIS + f*10 + p] = v[p] * inv;
  }
}

#define MFMA __builtin_amdgcn_mfma_f32_16x16x32_bf16

// ---------------------------------------------------------------------------
// Fully fused, all-MFMA MLP (bf16x3) + softmax/tanh tail + combine.
// 32 rows/block, 512 threads (8 waves), grid 512 (2 blocks/CU) — the r14
// verified structure. P7 stores are nontemporal (write-once stream, skip
// L2/L3 write-allocate); nontemporal via native ext_vector f32x4.
// ---------------------------------------------------------------------------
__global__ __launch_bounds__(512, 4) void fused_kernel(
    const float* __restrict__ x,
    const float* __restrict__ cb1, const float* __restrict__ cb2, const float* __restrict__ cb3,
    const float* __restrict__ wb1, const float* __restrict__ wb2, const float* __restrict__ wb3,
    const float* __restrict__ ws, float* __restrict__ out)
{
  __shared__ unsigned short H2A[16384];   // h2 A-frags [2 mt][8 kt]; [0..8192) aliases XA
  __shared__ unsigned short H1A[8192];    // h1 A-frags [2 mt][4 kt]
  __shared__ unsigned short HV1A[4096];   // hv1 A-frags [2 mt][2 kt]
  __shared__ unsigned short HV2A[8192];   // hv2 A-frags [2 mt][4 kt]
  __shared__ float vbuf[320];             // logits -> softmax w [32][10]
  __shared__ float cpbuf[640];            // cp sums -> wm [32][20]

  const int tid = threadIdx.x;
  const int l   = tid & 63;
  const int w   = tid >> 6;     // 0..7
  const int g   = l >> 4;       // 0..3
  const int c16 = l & 15;
  const int b0  = blockIdx.x * 32;
  unsigned short* XA = H2A;     // x A-frags [2 mt][4 kt], dead after B2
  const unsigned short* wsU = (const unsigned short*)ws;

  // ---- P0: load x, split hi/lo, write XA frags
  {
    int r = tid >> 4, k8 = tid & 15;
    const f32x4* xg = (const f32x4*)(x + (size_t)(b0 + r) * 128 + k8 * 8);
    f32x4 v0 = __builtin_nontemporal_load(xg);
    f32x4 v1 = __builtin_nontemporal_load(xg + 1);
    float xv[8] = {v0[0], v0[1], v0[2], v0[3], v1[0], v1[1], v1[2], v1[3]};
    bf16x8 hv, lv;
    #pragma unroll
    for (int j = 0; j < 8; ++j) {
      unsigned short h = f2bf(xv[j]);
      hv[j] = (short)h;
      lv[j] = (short)f2bf(xv[j] - bf2f(h));
    }
    int kt = k8 >> 2;
    int tile = (r >> 4) * 4 + kt;
    int s = (r & 15) + 16 * (k8 & 3);
    unsigned short* dst = XA + tile * 1024 + fslot(s, kt) * 8;
    *(bf16x8*)dst = hv;
    *(bf16x8*)(dst + 512) = lv;
  }

  // P1P2 pointers + kt0 B-frag prefetch (global, legal before barrier)
  const int mt  = w >> 2;            // row tile 0..1
  const int ntv = w & 3;             // V1 col tile
  const int nt0 = (w & 3) * 2, nt1 = nt0 + 1;  // L1 col tiles
  const unsigned short* BV  = wsU + OFF_FV1*2 + (ntv*4)*1024 + l*8;
  const unsigned short* BL0 = wsU + OFF_F1*2  + (nt0*4)*1024 + l*8;
  const unsigned short* BL1 = wsU + OFF_F1*2  + (nt1*4)*1024 + l*8;
  bf16x8 nvh = *(const bf16x8*)BV;        bf16x8 nvl = *(const bf16x8*)(BV + 512);
  bf16x8 n0h = *(const bf16x8*)BL0;       bf16x8 n0l = *(const bf16x8*)(BL0 + 512);
  bf16x8 n1h = *(const bf16x8*)BL1;       bf16x8 n1l = *(const bf16x8*)(BL1 + 512);

  __syncthreads();   // B1: XA ready

  // ---- P1P2: V1 (1 tile) + L1 (2 tiles) fused over kt, B rotated
  {
    float bv  = wb1[ntv*16 + c16];
    float bl0 = cb1[nt0*16 + c16], bl1 = cb1[nt1*16 + c16];
    f32x4 aVA = {bv, bv, bv, bv},     aVB = {0.f, 0.f, 0.f, 0.f};
    f32x4 aL0A = {bl0, bl0, bl0, bl0}, aL0B = {0.f, 0.f, 0.f, 0.f};
    f32x4 aL1A = {bl1, bl1, bl1, bl1}, aL1B = {0.f, 0.f, 0.f, 0.f};
    #pragma unroll
    for (int kt = 0; kt < 4; ++kt) {
      bf16x8 vh = nvh, vl = nvl, b0h_ = n0h, b0l_ = n0l, b1h_ = n1h, b1l_ = n1l;
      if (kt < 3) {
        nvh = *(const bf16x8*)(BV  + (kt+1)*1024); nvl = *(const bf16x8*)(BV  + (kt+1)*1024 + 512);
        n0h = *(const bf16x8*)(BL0 + (kt+1)*1024); n0l = *(const bf16x8*)(BL0 + (kt+1)*1024 + 512);
        n1h = *(const bf16x8*)(BL1 + (kt+1)*1024); n1l = *(const bf16x8*)(BL1 + (kt+1)*1024 + 512);
      }
      const unsigned short* ap = XA + (mt*4 + kt) * 1024 + fslot(l, kt) * 8;
      bf16x8 ah = *(const bf16x8*)ap;
      bf16x8 al = *(const bf16x8*)(ap + 512);
      aVA = MFMA(ah, vh, aVA, 0,0,0);   aVB = MFMA(ah, vl, aVB, 0,0,0);   aVB = MFMA(al, vh, aVB, 0,0,0);
      aL0A = MFMA(ah, b0h_, aL0A, 0,0,0); aL0B = MFMA(ah, b0l_, aL0B, 0,0,0); aL0B = MFMA(al, b0h_, aL0B, 0,0,0);
      aL1A = MFMA(ah, b1h_, aL1A, 0,0,0); aL1B = MFMA(ah, b1l_, aL1B, 0,0,0); aL1B = MFMA(al, b1h_, aL1B, 0,0,0);
    }
    // V1 epilogue -> HV1A (hv1 width 64)
    {
      int kt2 = ntv >> 1;
      int sb = 16 * ((2*ntv + (c16 >> 3)) & 3);
      unsigned short* tb = HV1A + (mt*2 + kt2) * 1024;
      #pragma unroll
      for (int i = 0; i < 4; ++i) {
        float v = fmaxf(aVA[i] + aVB[i], 0.f);
        int idx = fslot(4*g + i + sb, kt2) * 8 + (c16 & 7);
        unsigned short h = f2bf(v);
        tb[idx] = h; tb[512 + idx] = f2bf(v - bf2f(h));
      }
    }
    // L1 epilogue -> H1A (h1 width 128)
    #pragma unroll
    for (int t2 = 0; t2 < 2; ++t2) {
      int nt = nt0 + t2;
      int kt2 = nt >> 1;
      int sb = 16 * ((2*nt + (c16 >> 3)) & 3);
      unsigned short* tb = H1A + (mt*4 + kt2) * 1024;
      #pragma unroll
      for (int i = 0; i < 4; ++i) {
        float v = t2 ? fmaxf(aL1A[i] + aL1B[i], 0.f) : fmaxf(aL0A[i] + aL0B[i], 0.f);
        int idx = fslot(4*g + i + sb, kt2) * 8 + (c16 & 7);
        unsigned short h = f2bf(v);
        tb[idx] = h; tb[512 + idx] = f2bf(v - bf2f(h));
      }
    }
  }

  // P3 B-frag preloads (V2: 2 tiles x 2 kt), issued before the barrier
  const int v0t = (w & 3) * 2, v1t = v0t + 1;   // hv2 col tiles 0..7
  const unsigned short* C0 = wsU + OFF_FV2*2 + (v0t*2)*1024 + l*8;
  const unsigned short* C1 = wsU + OFF_FV2*2 + (v1t*2)*1024 + l*8;
  bf16x8 c0h0 = *(const bf16x8*)C0;          bf16x8 c0l0 = *(const bf16x8*)(C0 + 512);
  bf16x8 c0h1 = *(const bf16x8*)(C0 + 1024); bf16x8 c0l1 = *(const bf16x8*)(C0 + 1536);
  bf16x8 c1h0 = *(const bf16x8*)C1;          bf16x8 c1l0 = *(const bf16x8*)(C1 + 512);
  bf16x8 c1h1 = *(const bf16x8*)(C1 + 1024); bf16x8 c1l1 = *(const bf16x8*)(C1 + 1536);

  // P4 pp=0 kt0 B-frag prefetch (global, read-only -> safe before barrier)
  const int m0p = (w & 3) * 4, m1p = m0p + 1;
  const unsigned short* D0p = wsU + OFF_F2*2 + (m0p*4)*1024 + l*8;
  const unsigned short* D1p = wsU + OFF_F2*2 + (m1p*4)*1024 + l*8;
  bf16x8 pd0h = *(const bf16x8*)D0p, pd0l = *(const bf16x8*)(D0p + 512);
  bf16x8 pd1h = *(const bf16x8*)D1p, pd1l = *(const bf16x8*)(D1p + 512);

  __syncthreads();   // B2: H1A/HV1A ready, XA dead

  // ---- P3: V2 (2 tiles/wave, K=64) -> HV2A frags
  {
    float bb0 = wb2[v0t*16 + c16], bb1 = wb2[v1t*16 + c16];
    f32x4 a0A = {bb0, bb0, bb0, bb0}, a0B = {0.f, 0.f, 0.f, 0.f};
    f32x4 a1A = {bb1, bb1, bb1, bb1}, a1B = {0.f, 0.f, 0.f, 0.f};
    {
      const unsigned short* ap = HV1A + (mt*2 + 0) * 1024 + fslot(l, 0) * 8;
      bf16x8 ah = *(const bf16x8*)ap, al = *(const bf16x8*)(ap + 512);
      a0A = MFMA(ah, c0h0, a0A, 0,0,0); a0B = MFMA(ah, c0l0, a0B, 0,0,0); a0B = MFMA(al, c0h0, a0B, 0,0,0);
      a1A = MFMA(ah, c1h0, a1A, 0,0,0); a1B = MFMA(ah, c1l0, a1B, 0,0,0); a1B = MFMA(al, c1h0, a1B, 0,0,0);
    }
    {
      const unsigned short* ap = HV1A + (mt*2 + 1) * 1024 + fslot(l, 1) * 8;
      bf16x8 ah = *(const bf16x8*)ap, al = *(const bf16x8*)(ap + 512);
      a0A = MFMA(ah, c0h1, a0A, 0,0,0); a0B = MFMA(ah, c0l1, a0B, 0,0,0); a0B = MFMA(al, c0h1, a0B, 0,0,0);
      a1A = MFMA(ah, c1h1, a1A, 0,0,0); a1B = MFMA(ah, c1l1, a1B, 0,0,0); a1B = MFMA(al, c1h1, a1B, 0,0,0);
    }
    #pragma unroll
    for (int t2 = 0; t2 < 2; ++t2) {
      int nt = v0t + t2;
      int kt2 = nt >> 1;
      int sb = 16 * ((2*nt + (c16 >> 3)) & 3);
      unsigned short* tb = HV2A + (mt*4 + kt2) * 1024;
      #pragma unroll
      for (int i = 0; i < 4; ++i) {
        float v = t2 ? fmaxf(a1A[i] + a1B[i], 0.f) : fmaxf(a0A[i] + a0B[i], 0.f);
        int idx = fslot(4*g + i + sb, kt2) * 8 + (c16 & 7);
        unsigned short h = f2bf(v);
        tb[idx] = h; tb[512 + idx] = f2bf(v - bf2f(h));
      }
    }
  }

  // ---- P4: L2 (4 tiles/wave in 2 pairs, K=128) -> H2A frags, B rotated
  #pragma unroll
  for (int pp = 0; pp < 2; ++pp) {
    const int m0 = (w & 3) * 4 + pp * 2, m1 = m0 + 1;   // h2 col tiles 0..15
    const unsigned short* D0 = wsU + OFF_F2*2 + (m0*4)*1024 + l*8;
    const unsigned short* D1 = wsU + OFF_F2*2 + (m1*4)*1024 + l*8;
    bf16x8 nd0h = pp ? *(const bf16x8*)D0 : pd0h;
    bf16x8 nd0l = pp ? *(const bf16x8*)(D0 + 512) : pd0l;
    bf16x8 nd1h = pp ? *(const bf16x8*)D1 : pd1h;
    bf16x8 nd1l = pp ? *(const bf16x8*)(D1 + 512) : pd1l;
    float bb0 = cb2[m0*16 + c16], bb1 = cb2[m1*16 + c16];
    f32x4 a0A = {bb0, bb0, bb0, bb0}, a0B = {0.f, 0.f, 0.f, 0.f};
    f32x4 a1A = {bb1, bb1, bb1, bb1}, a1B = {0.f, 0.f, 0.f, 0.f};
    #pragma unroll
    for (int kt = 0; kt < 4; ++kt) {
      bf16x8 d0h = nd0h, d0l = nd0l, d1h = nd1h, d1l = nd1l;
      if (kt < 3) {
        nd0h = *(const bf16x8*)(D0 + (kt+1)*1024); nd0l = *(const bf16x8*)(D0 + (kt+1)*1024 + 512);
        nd1h = *(const bf16x8*)(D1 + (kt+1)*1024); nd1l = *(const bf16x8*)(D1 + (kt+1)*1024 + 512);
      }
      const unsigned short* ap = H1A + (mt*4 + kt) * 1024 + fslot(l, kt) * 8;
      bf16x8 ah = *(const bf16x8*)ap, al = *(const bf16x8*)(ap + 512);
      a0A = MFMA(ah, d0h, a0A, 0,0,0); a0B = MFMA(ah, d0l, a0B, 0,0,0); a0B = MFMA(al, d0h, a0B, 0,0,0);
      a1A = MFMA(ah, d1h, a1A, 0,0,0); a1B = MFMA(ah, d1l, a1B, 0,0,0); a1B = MFMA(al, d1h, a1B, 0,0,0);
    }
    #pragma unroll
    for (int t2 = 0; t2 < 2; ++t2) {
      int nt = m0 + t2;
      int kt2 = nt >> 1;
      int sb = 16 * ((2*nt + (c16 >> 3)) & 3);
      unsigned short* tb = H2A + (mt*8 + kt2) * 1024;
      #pragma unroll
      for (int i = 0; i < 4; ++i) {
        float v = t2 ? fmaxf(a1A[i] + a1B[i], 0.f) : fmaxf(a0A[i] + a0B[i], 0.f);
        int idx = fslot(4*g + i + sb, kt2) * 8 + (c16 & 7);
        unsigned short h = f2bf(v);
        tb[idx] = h; tb[512 + idx] = f2bf(v - bf2f(h));
      }
    }
  }

  // P5 kt0 B-frag prefetch + tail basis hoist (global, safe before barrier)
  bf16x8 p5h = {}, p5l = {};
  if (w < 4) {
    const unsigned short* F3p = wsU + OFF_F3*2 + ((w & 1)*8)*1024 + l*8;
    p5h = *(const bf16x8*)F3p; p5l = *(const bf16x8*)(F3p + 512);
  } else if (w < 6) {
    const unsigned short* FVp = wsU + OFF_FV3*2 + l*8;
    p5h = *(const bf16x8*)FVp; p5l = *(const bf16x8*)(FVp + 512);
  }
  // P7 geometry: half = row half, 4 consecutive f-cols per thread.
  const int half  = tid >> 8;            // 0: rows 0-15, 1: rows 16-31
  const int rbase = half * 16;
  const int f0    = (tid & 255) * 4;
  float bas[4][10];
  {
    const float* BAS = ws + OFF_BASIS;
    #pragma unroll
    for (int i = 0; i < 4; ++i) {
      const float2* bp = (const float2*)(BAS + (f0 + i) * 10);
      #pragma unroll
      for (int p = 0; p < 5; ++p) { float2 v = bp[p]; bas[i][2*p] = v.x; bas[i][2*p+1] = v.y; }
    }
  }
  __syncthreads();   // B3: H2A/HV2A ready

  // ---- P5: V3+L3 via MFMA (unique owners -> plain LDS stores)
  if (w < 4) {        // L3: tile (lmt = w>>1, lnt = w&1), K=256
    const int lmt = w >> 1, lnt = w & 1;
    const unsigned short* F3 = wsU + OFF_F3*2 + (lnt*8)*1024 + l*8;
    f32x4 aA = {0.f, 0.f, 0.f, 0.f}, aB = {0.f, 0.f, 0.f, 0.f};
    bf16x8 nbh = p5h, nbl = p5l;
    #pragma unroll
    for (int kt = 0; kt < 8; ++kt) {
      bf16x8 bh = nbh, bl = nbl;
      if (kt < 7) {
        nbh = *(const bf16x8*)(F3 + (kt+1)*1024); nbl = *(const bf16x8*)(F3 + (kt+1)*1024 + 512);
      }
      const unsigned short* ap = H2A + (lmt*8 + kt) * 1024 + fslot(l, kt) * 8;
      bf16x8 ah = *(const bf16x8*)ap, al = *(const bf16x8*)(ap + 512);
      aA = MFMA(ah, bh, aA, 0,0,0); aB = MFMA(ah, bl, aB, 0,0,0); aB = MFMA(al, bh, aB, 0,0,0);
    }
    #pragma unroll
    for (int i = 0; i < 4; ++i) {
      int r = lmt*16 + 4*g + i, c = lnt*16 + c16;
      if (c < 20) cpbuf[r*20 + c] = aA[i] + aB[i];
    }
  } else if (w < 6) { // V3: tile (vmt = w-4), K=128
    const int vmt = w - 4;
    const unsigned short* FV = wsU + OFF_FV3*2 + l*8;
    f32x4 aA = {0.f, 0.f, 0.f, 0.f}, aB = {0.f, 0.f, 0.f, 0.f};
    #pragma unroll
    for (int kt = 0; kt < 4; ++kt) {
      bf16x8 bh = kt ? *(const bf16x8*)(FV + kt*1024) : p5h;
      bf16x8 bl = kt ? *(const bf16x8*)(FV + kt*1024 + 512) : p5l;
      const unsigned short* ap = HV2A + (vmt*4 + kt) * 1024 + fslot(l, kt) * 8;
      bf16x8 ah = *(const bf16x8*)ap, al = *(const bf16x8*)(ap + 512);
      aA = MFMA(ah, bh, aA, 0,0,0); aB = MFMA(ah, bl, aB, 0,0,0); aB = MFMA(al, bh, aB, 0,0,0);
    }
    #pragma unroll
    for (int i = 0; i < 4; ++i) {
      int r = vmt*16 + 4*g + i;
      if (c16 < 10) vbuf[r*10 + c16] = aA[i] + aB[i];
    }
  }
  __syncthreads();   // B4: vbuf(logits) + cpbuf(cp sums) ready

  // ---- P6: softmax + wm (tid<32, one row each)
  if (tid < 32) {
    float lg[10]; float m = -1e30f;
    #pragma unroll
    for (int j = 0; j < 10; ++j) { lg[j] = vbuf[tid*10 + j] + wb3[j]; m = fmaxf(m, lg[j]); }
    float s = 0.f;
    #pragma unroll
    for (int j = 0; j < 10; ++j) { float e = expf(lg[j] - m); lg[j] = e; s += e; }
    float inv = __builtin_amdgcn_rcpf(s);
    #pragma unroll
    for (int j = 0; j < 10; ++j) vbuf[tid*10 + j] = lg[j] * inv;
    #pragma unroll
    for (int p = 0; p < 10; ++p) {
      float s0 = cpbuf[tid*20 + 2*p]     + cb3[2*p];
      float s1 = cpbuf[tid*20 + 2*p + 1] + cb3[2*p + 1];
      float cm = 0.5f * (tanhf(s0) + tanhf(s1));
      cpbuf[tid*20 + p] = vbuf[tid*10 + p] * cm;
    }
  }
  __syncthreads();   // B5: w in vbuf[.][0..10), wm in cpbuf[.*20 + 0..10)

  // ---- P7: combine + output. thread = 4 consecutive f-cols x 16 rows
  // (row half by tid>>8); nontemporal f32x4 stores (write-once stream).
  for (int rr = 0; rr < 16; ++rr) {
    const int r = rbase + rr;
    float wv[10], wm[10];
    #pragma unroll
    for (int p = 0; p < 10; p += 2) {
      float2 a = *(const float2*)(vbuf + r*10 + p);
      wv[p] = a.x; wv[p+1] = a.y;
      float2 b = *(const float2*)(cpbuf + r*20 + p);
      wm[p] = b.x; wm[p+1] = b.y;
    }
    f32x4 o;
    float n, d;
    n = 0.f; d = EPS;
    #pragma unroll
    for (int p = 0; p < 10; ++p) { n = fmaf(bas[0][p], wm[p], n); d = fmaf(bas[0][p], wv[p], d); }
    o[0] = n * __builtin_amdgcn_rcpf(d);
    n = 0.f; d = EPS;
    #pragma unroll
    for (int p = 0; p < 10; ++p) { n = fmaf(bas[1][p], wm[p], n); d = fmaf(bas[1][p], wv[p], d); }
    o[1] = n * __builtin_amdgcn_rcpf(d);
    n = 0.f; d = EPS;
    #pragma unroll
    for (int p = 0; p < 10; ++p) { n = fmaf(bas[2][p], wm[p], n); d = fmaf(bas[2][p], wv[p], d); }
    o[2] = n * __builtin_amdgcn_rcpf(d);
    n = 0.f; d = EPS;
    #pragma unroll
    for (int p = 0; p < 10; ++p) { n = fmaf(bas[3][p], wm[p], n); d = fmaf(bas[3][p], wv[p], d); }
    o[3] = n * __builtin_amdgcn_rcpf(d);
    __builtin_nontemporal_store(o, (f32x4*)(out + (size_t)(b0 + r) * 1024 + f0));
  }
}

// ---------------------------------------------------------------------------
extern "C" void kernel_launch(void* const* d_in, const int* in_sizes, int n_in,
                              void* d_out, int out_size, void* d_ws, size_t ws_size,
                              hipStream_t stream)
{
  const float* x   = (const float*)d_in[0];
  const float* cw1 = (const float*)d_in[1];
  const float* cb1 = (const float*)d_in[2];
  const float* cw2 = (const float*)d_in[3];
  const float* cb2 = (const float*)d_in[4];
  const float* cw3 = (const float*)d_in[5];
  const float* cb3 = (const float*)d_in[6];
  const float* ww1 = (const float*)d_in[7];
  const float* wb1 = (const float*)d_in[8];
  const float* ww2 = (const float*)d_in[9];
  const float* wb2 = (const float*)d_in[10];
  const float* ww3 = (const float*)d_in[11];
  const float* wb3 = (const float*)d_in[12];
  float* ws  = (float*)d_ws;
  float* out = (float*)d_out;

  prep_kernel<<<41, 256, 0, stream>>>(cw1, cw2, cw3, ww1, ww2, ww3, ws);
  fused_kernel<<<512, 512, 0, stream>>>(x, cb1, cb2, cb3, wb1, wb2, wb3, ws, out);
}